// Round 5
// baseline (630.904 us; speedup 1.0000x reference)
//
#include <hip/hip_runtime.h>
#include <hip/hip_bf16.h>
#include <hip/hip_fp16.h>

// ---------------------------------------------------------------------------
// MPNN binding-affinity predictor. R5:
//  - activations stored as bf16 hi/lo planes; GEMM A/B staging is pure
//    global_load_lds (16B DMA) with XOR-swizzled conflict-free LDS layout
//  - 64x128 tiles, 2x2 waves, 24 MFMA / 12 ds_read_b128 / 6 gld-lds per k-iter
//  - atom pre-converted to planes; aggregate emits hi/lo planes
// ---------------------------------------------------------------------------

#define HID 256

typedef short short8 __attribute__((ext_vector_type(8)));
typedef float f32x4 __attribute__((ext_vector_type(4)));

__device__ __forceinline__ unsigned short bf_rne(float f) {
    unsigned u = __float_as_uint(f);
    u += 0x7fffu + ((u >> 16) & 1u);
    return (unsigned short)(u >> 16);
}

__device__ __forceinline__ void split_pack8(const float* f, int4& hp, int4& lp) {
    unsigned short h[8], l[8];
#pragma unroll
    for (int j = 0; j < 8; ++j) {
        unsigned short hh = bf_rne(f[j]);
        float fh = __uint_as_float((unsigned)hh << 16);
        h[j] = hh;
        l[j] = bf_rne(f[j] - fh);
    }
    hp.x = (int)(h[0] | ((unsigned)h[1] << 16));
    hp.y = (int)(h[2] | ((unsigned)h[3] << 16));
    hp.z = (int)(h[4] | ((unsigned)h[5] << 16));
    hp.w = (int)(h[6] | ((unsigned)h[7] << 16));
    lp.x = (int)(l[0] | ((unsigned)l[1] << 16));
    lp.y = (int)(l[2] | ((unsigned)l[3] << 16));
    lp.z = (int)(l[4] | ((unsigned)l[5] << 16));
    lp.w = (int)(l[6] | ((unsigned)l[7] << 16));
}

__device__ __forceinline__ void unpack_h8(const int4& r, float* f) {
    const __half2* h = reinterpret_cast<const __half2*>(&r);
#pragma unroll
    for (int k = 0; k < 4; ++k) {
        float2 t = __half22float2(h[k]);
        f[2 * k] = t.x;
        f[2 * k + 1] = t.y;
    }
}

// async global -> LDS 16B DMA; dest = wave-uniform base + lane*16
__device__ __forceinline__ void gld16(const void* g, void* l) {
    __builtin_amdgcn_global_load_lds(
        (const __attribute__((address_space(1))) void*)g,
        (__attribute__((address_space(3))) void*)l, 16, 0, 0);
}

// XOR swizzle: k-segment permutation per row; <=2-way LDS conflicts (free)
__device__ __forceinline__ int swz(int row) { return (row + (row >> 2)) & 3; }

// ------------------------------ CSR build ----------------------------------

__global__ void hist_kernel(const int* __restrict__ dst, int* __restrict__ deg, int E) {
    int i = blockIdx.x * blockDim.x + threadIdx.x;
    if (i < E) atomicAdd(&deg[dst[i]], 1);
}

__global__ __launch_bounds__(256) void scan_kernel(
    const int* __restrict__ deg, int* __restrict__ offs, float* __restrict__ degf, int n) {
    __shared__ int ws[4];
    const int t = threadIdx.x;
    const int lane = t & 63;
    const int w = t >> 6;
    const int per = (n + 255) / 256;
    const int s = t * per;
    const int e = min(s + per, n);
    int sum = 0;
    for (int i = s; i < e; ++i) sum += deg[i];
    int v = sum;
#pragma unroll
    for (int off = 1; off < 64; off <<= 1) {
        int u = __shfl_up(v, off, 64);
        if (lane >= off) v += u;
    }
    if (lane == 63) ws[w] = v;
    __syncthreads();
    if (t == 0) {
        int c = 0;
#pragma unroll
        for (int i = 0; i < 4; ++i) { int x = ws[i]; ws[i] = c; c += x; }
    }
    __syncthreads();
    int run = ws[w] + v - sum;
    for (int i = s; i < e; ++i) {
        int d = deg[i];
        offs[i] = run;
        degf[i] = (float)d;
        run += d;
    }
    if (e == n) offs[n] = run;
}

__global__ void scatter_kernel(const int* __restrict__ src, const int* __restrict__ dst,
                               const int* __restrict__ offs, int* __restrict__ cursor,
                               int* __restrict__ csr_src, const float* __restrict__ ef,
                               __half* __restrict__ ef8, int E) {
    int i = blockIdx.x * blockDim.x + threadIdx.x;
    if (i < E) {
        int d = dst[i];
        int pos = atomicAdd(&cursor[d], 1);
        int idx = offs[d] + pos;
        csr_src[idx] = src[i];
        const float* s6 = ef + (size_t)i * 6;
        unsigned short h[8];
#pragma unroll
        for (int j = 0; j < 6; ++j) h[j] = __half_as_ushort(__float2half_rn(s6[j]));
        h[6] = 0; h[7] = 0;
        int4 pk;
        pk.x = (int)(h[0] | ((unsigned)h[1] << 16));
        pk.y = (int)(h[2] | ((unsigned)h[3] << 16));
        pk.z = (int)(h[4] | ((unsigned)h[5] << 16));
        pk.w = (int)(h[6] | ((unsigned)h[7] << 16));
        *reinterpret_cast<int4*>(ef8 + (size_t)idx * 8) = pk;
    }
}

// ----------------------- folded bias vectors -------------------------------

struct BDesc { float* out; const float* base; const float* v1; const float* B1;
               const float* v2; const float* B2; };
struct BTab { BDesc d[19]; };

__global__ __launch_bounds__(256) void biasvec_kernel(BTab tab) {
    const BDesc d = tab.d[blockIdx.x];
    const int j = threadIdx.x;
    float acc = d.base ? d.base[j] : 0.f;
    if (d.v1)
        for (int k = 0; k < 256; ++k) acc = fmaf(d.v1[k], d.B1[(size_t)k * 256 + j], acc);
    if (d.v2)
        for (int k = 0; k < 256; ++k) acc = fmaf(d.v2[k], d.B2[(size_t)k * 256 + j], acc);
    d.out[j] = acc;
}

// ------------------------ weight convert -----------------------------------
// src [Kreal, srcN] fp32 row-major -> dh/dl [srcN][Kpad] bf16 hi/lo.

struct CDesc {
    const float* src;
    unsigned short* dh;
    unsigned short* dl;
    int Kreal, Kpad, srcN, tile0;
};
struct CTab {
    CDesc d[32];
    int nd;
};

__global__ __launch_bounds__(256) void convert_weights(CTab tab) {
    const int bid = blockIdx.x;
    int idx = 0;
    for (int i = 1; i < tab.nd; ++i)
        if (tab.d[i].tile0 <= bid) idx = i;
    const CDesc d = tab.d[idx];
    const int q = bid - d.tile0;
    const int ntN = d.srcN >> 6;
    const int kb = (q / ntN) * 32;
    const int nb = (q % ntN) * 64;
    const int n = nb + (threadIdx.x & 63);
    const int k0 = kb + (threadIdx.x >> 6) * 8;
    float f[8];
#pragma unroll
    for (int j = 0; j < 8; ++j) {
        int k = k0 + j;
        f[j] = (k < d.Kreal) ? d.src[(size_t)k * d.srcN + n] : 0.f;
    }
    int4 hp, lp;
    split_pack8(f, hp, lp);
    *reinterpret_cast<int4*>(&d.dh[(size_t)n * d.Kpad + k0]) = hp;
    *reinterpret_cast<int4*>(&d.dl[(size_t)n * d.Kpad + k0]) = lp;
}

// ------------------- activation fp32 -> hi/lo planes -----------------------
// src [rows, scols] fp32 -> dst/dst+ps [rows, dcols] bf16 (pad with 0)

__global__ __launch_bounds__(256) void act_convert(
    const float* __restrict__ src, unsigned short* __restrict__ dst, long ps,
    int rows, int scols, int dcols) {
    const int nseg = dcols >> 3;
    int t = blockIdx.x * blockDim.x + threadIdx.x;
    if (t >= rows * nseg) return;
    int r = t / nseg, seg = t - r * nseg;
    float f[8];
#pragma unroll
    for (int j = 0; j < 8; ++j) {
        int c = seg * 8 + j;
        f[j] = (c < scols) ? src[(size_t)r * scols + c] : 0.f;
    }
    int4 hp, lp;
    split_pack8(f, hp, lp);
    *reinterpret_cast<int4*>(&dst[(size_t)r * dcols + seg * 8]) = hp;
    *reinterpret_cast<int4*>(&dst[ps + (size_t)r * dcols + seg * 8]) = lp;
}

// ------------------- batched fold GEMM on matrix cores ---------------------
// C[256,256] = A[256,256](fp32, runtime split) @ B(bf16 hi/lo [n][k]).

#define ASTR 40

struct FDesc { const float* A; const unsigned short* Bh; const unsigned short* Bl; float* C; };
struct FTab { FDesc d[22]; };

__global__ __launch_bounds__(256) void fold_gemm(FTab tab) {
    const FDesc dd = tab.d[blockIdx.x >> 4];
    const int t4 = blockIdx.x & 15;
    const int rowBase = (t4 >> 2) * 64;
    const int colBase = (t4 & 3) * 64;

    __shared__ __align__(16) unsigned short Ah[64 * ASTR];
    __shared__ __align__(16) unsigned short Al[64 * ASTR];
    __shared__ __align__(16) unsigned short Bh[64 * ASTR];
    __shared__ __align__(16) unsigned short Bl[64 * ASTR];

    const int tid = threadIdx.x;
    const int lane = tid & 63;
    const int wave = tid >> 6;
    const int waveM = (wave >> 1) * 32;
    const int waveN = (wave & 1) * 32;
    const int m0 = lane & 15;
    const int quad = lane >> 4;
    const int sr = tid >> 2;
    const int sseg = tid & 3;

    const f32x4 z = {0.f, 0.f, 0.f, 0.f};
    f32x4 acc[2][2] = {{z, z}, {z, z}};

    for (int kb = 0; kb < 256; kb += 32) {
        {
            const float* Ap = dd.A + (size_t)(rowBase + sr) * 256 + kb + sseg * 8;
            float f[8];
            float4 u0 = *reinterpret_cast<const float4*>(Ap);
            float4 u1 = *reinterpret_cast<const float4*>(Ap + 4);
            f[0] = u0.x; f[1] = u0.y; f[2] = u0.z; f[3] = u0.w;
            f[4] = u1.x; f[5] = u1.y; f[6] = u1.z; f[7] = u1.w;
            int4 hp, lp;
            split_pack8(f, hp, lp);
            *reinterpret_cast<int4*>(&Ah[sr * ASTR + sseg * 8]) = hp;
            *reinterpret_cast<int4*>(&Al[sr * ASTR + sseg * 8]) = lp;
        }
        {
            size_t off = (size_t)(colBase + sr) * 256 + kb + sseg * 8;
            *reinterpret_cast<int4*>(&Bh[sr * ASTR + sseg * 8]) =
                *reinterpret_cast<const int4*>(&dd.Bh[off]);
            *reinterpret_cast<int4*>(&Bl[sr * ASTR + sseg * 8]) =
                *reinterpret_cast<const int4*>(&dd.Bl[off]);
        }
        __syncthreads();

        const short8 a0h = *reinterpret_cast<const short8*>(&Ah[(waveM + m0) * ASTR + quad * 8]);
        const short8 a1h = *reinterpret_cast<const short8*>(&Ah[(waveM + 16 + m0) * ASTR + quad * 8]);
        const short8 a0l = *reinterpret_cast<const short8*>(&Al[(waveM + m0) * ASTR + quad * 8]);
        const short8 a1l = *reinterpret_cast<const short8*>(&Al[(waveM + 16 + m0) * ASTR + quad * 8]);
        const short8 b0h = *reinterpret_cast<const short8*>(&Bh[(waveN + m0) * ASTR + quad * 8]);
        const short8 b1h = *reinterpret_cast<const short8*>(&Bh[(waveN + 16 + m0) * ASTR + quad * 8]);
        const short8 b0l = *reinterpret_cast<const short8*>(&Bl[(waveN + m0) * ASTR + quad * 8]);
        const short8 b1l = *reinterpret_cast<const short8*>(&Bl[(waveN + 16 + m0) * ASTR + quad * 8]);

        acc[0][0] = __builtin_amdgcn_mfma_f32_16x16x32_bf16(a0h, b0h, acc[0][0], 0, 0, 0);
        acc[0][1] = __builtin_amdgcn_mfma_f32_16x16x32_bf16(a0h, b1h, acc[0][1], 0, 0, 0);
        acc[1][0] = __builtin_amdgcn_mfma_f32_16x16x32_bf16(a1h, b0h, acc[1][0], 0, 0, 0);
        acc[1][1] = __builtin_amdgcn_mfma_f32_16x16x32_bf16(a1h, b1h, acc[1][1], 0, 0, 0);
        acc[0][0] = __builtin_amdgcn_mfma_f32_16x16x32_bf16(a0l, b0h, acc[0][0], 0, 0, 0);
        acc[0][1] = __builtin_amdgcn_mfma_f32_16x16x32_bf16(a0l, b1h, acc[0][1], 0, 0, 0);
        acc[1][0] = __builtin_amdgcn_mfma_f32_16x16x32_bf16(a1l, b0h, acc[1][0], 0, 0, 0);
        acc[1][1] = __builtin_amdgcn_mfma_f32_16x16x32_bf16(a1l, b1h, acc[1][1], 0, 0, 0);
        acc[0][0] = __builtin_amdgcn_mfma_f32_16x16x32_bf16(a0h, b0l, acc[0][0], 0, 0, 0);
        acc[0][1] = __builtin_amdgcn_mfma_f32_16x16x32_bf16(a0h, b1l, acc[0][1], 0, 0, 0);
        acc[1][0] = __builtin_amdgcn_mfma_f32_16x16x32_bf16(a1h, b0l, acc[1][0], 0, 0, 0);
        acc[1][1] = __builtin_amdgcn_mfma_f32_16x16x32_bf16(a1h, b1l, acc[1][1], 0, 0, 0);

        __syncthreads();
    }

#pragma unroll
    for (int tm = 0; tm < 2; ++tm)
#pragma unroll
        for (int reg = 0; reg < 4; ++reg) {
            int row = rowBase + waveM + tm * 16 + quad * 4 + reg;
#pragma unroll
            for (int tn = 0; tn < 2; ++tn) {
                int col = colBase + waveN + tn * 16 + m0;
                dd.C[(size_t)row * 256 + col] = acc[tm][tn][reg];
            }
        }
}

// ------------------------------ MFMA GEMM ----------------------------------
// C = act( A1@W1 (+ A2@W2) + bias + rowscale.*bias2 ).
// A: bf16 hi/lo planes [M][lda] (+ aps). W: bf16 hi/lo planes [Nc][K] (+ wps).
// Tile 64x128, BK=32; 4 waves 2x2 (wave tile 32x64). All staging via
// global_load_lds 16B DMA into XOR-swizzled LDS. Output planes or fp16.

__global__ __launch_bounds__(256) void mfma_gemm(
    const unsigned short* __restrict__ A1, int lda1, long aps1,
    const unsigned short* __restrict__ W1, long wps1, int K1,
    const unsigned short* __restrict__ A2, int lda2, long aps2,
    const unsigned short* __restrict__ W2, long wps2, int K2,
    const float* __restrict__ bias, const float* __restrict__ bias2,
    const float* __restrict__ rowscale,
    unsigned short* __restrict__ Cp, long cps, __half* __restrict__ Ch,
    int M, int Nc, int do_relu) {
    // regions: Ah[0,4K) Al[4K,8K) Bh[8K,16K) Bl[16K,24K)
    __shared__ __align__(16) unsigned char lds[24576];

    const int tid = threadIdx.x;
    const int lane = tid & 63;
    const int wave = tid >> 6;
    const int m0 = lane & 15;
    const int quad = lane >> 4;
    const int waveM = (wave >> 1) * 32;
    const int waveN = (wave & 1) * 64;
    const int rowBase = blockIdx.x * 64;
    const int colBase = blockIdx.y * 128;

    // staging decode (constant per thread): slot s holds kseg s^swz(row)
    const int sa_r = tid >> 2;
    const int sa_ks = (tid & 3) ^ swz(sa_r);
    const int sa_row = min(rowBase + sa_r, M - 1);
    const int sb_r1 = sa_r + 64;
    const int sb_ks1 = (tid & 3) ^ swz(sb_r1);

    // fragment LDS offsets (constant across k-iters)
    int aoff[2], boff[4];
#pragma unroll
    for (int tm = 0; tm < 2; ++tm) {
        int r = waveM + tm * 16 + m0;
        aoff[tm] = ((r << 2) + (quad ^ swz(r))) << 4;
    }
#pragma unroll
    for (int tn = 0; tn < 4; ++tn) {
        int r = waveN + tn * 16 + m0;
        boff[tn] = ((r << 2) + (quad ^ swz(r))) << 4;
    }

    const f32x4 z = {0.f, 0.f, 0.f, 0.f};
    f32x4 acc[2][4] = {{z, z, z, z}, {z, z, z, z}};

    for (int pass = 0; pass < 2; ++pass) {
        const unsigned short* A = pass ? A2 : A1;
        if (!A) continue;
        const int lda = pass ? lda2 : lda1;
        const long aps = pass ? aps2 : aps1;
        const unsigned short* W = pass ? W2 : W1;
        const long wps = pass ? wps2 : wps1;
        const int K = pass ? K2 : K1;

        const unsigned short* ga = A + (size_t)sa_row * lda + sa_ks * 8;
        const unsigned short* gb0 = W + (size_t)(colBase + sa_r) * K + sa_ks * 8;
        const unsigned short* gb1 = W + (size_t)(colBase + sb_r1) * K + sb_ks1 * 8;

        for (int kb = 0; kb < K; kb += 32) {
            gld16(ga + kb, lds + wave * 1024);
            gld16(ga + aps + kb, lds + 4096 + wave * 1024);
            gld16(gb0 + kb, lds + 8192 + wave * 1024);
            gld16(gb1 + kb, lds + 12288 + wave * 1024);
            gld16(gb0 + wps + kb, lds + 16384 + wave * 1024);
            gld16(gb1 + wps + kb, lds + 20480 + wave * 1024);
            __syncthreads();

            short8 ah[2], al[2], bh[4], bl[4];
#pragma unroll
            for (int tm = 0; tm < 2; ++tm) {
                ah[tm] = *reinterpret_cast<const short8*>(lds + aoff[tm]);
                al[tm] = *reinterpret_cast<const short8*>(lds + 4096 + aoff[tm]);
            }
#pragma unroll
            for (int tn = 0; tn < 4; ++tn) {
                bh[tn] = *reinterpret_cast<const short8*>(lds + 8192 + boff[tn]);
                bl[tn] = *reinterpret_cast<const short8*>(lds + 16384 + boff[tn]);
            }
#pragma unroll
            for (int tm = 0; tm < 2; ++tm)
#pragma unroll
                for (int tn = 0; tn < 4; ++tn) {
                    acc[tm][tn] = __builtin_amdgcn_mfma_f32_16x16x32_bf16(ah[tm], bh[tn], acc[tm][tn], 0, 0, 0);
                    acc[tm][tn] = __builtin_amdgcn_mfma_f32_16x16x32_bf16(al[tm], bh[tn], acc[tm][tn], 0, 0, 0);
                    acc[tm][tn] = __builtin_amdgcn_mfma_f32_16x16x32_bf16(ah[tm], bl[tn], acc[tm][tn], 0, 0, 0);
                }
            __syncthreads();
        }
    }

    // epilogue
    float cb[4], db[4];
    int col[4];
#pragma unroll
    for (int tn = 0; tn < 4; ++tn) {
        col[tn] = colBase + waveN + tn * 16 + m0;
        cb[tn] = bias ? bias[col[tn]] : 0.f;
        db[tn] = bias2 ? bias2[col[tn]] : 0.f;
    }
#pragma unroll
    for (int tm = 0; tm < 2; ++tm) {
#pragma unroll
        for (int reg = 0; reg < 4; ++reg) {
            int row = rowBase + waveM + tm * 16 + quad * 4 + reg;
            if (row >= M) continue;
            float rs = rowscale ? rowscale[row] : 0.0f;
#pragma unroll
            for (int tn = 0; tn < 4; ++tn) {
                float v = acc[tm][tn][reg] + cb[tn] + rs * db[tn];
                if (do_relu) v = fmaxf(v, 0.f);
                size_t idx = (size_t)row * Nc + col[tn];
                if (Ch) {
                    Ch[idx] = __float2half_rn(v);
                } else {
                    unsigned short hh = bf_rne(v);
                    float fh = __uint_as_float((unsigned)hh << 16);
                    Cp[idx] = hh;
                    Cp[cps + idx] = bf_rne(v - fh);
                }
            }
        }
    }
}

// --------------------------- edge aggregation ------------------------------
// Hagg[v] = sum_{e=(s,v)} relu(P[s] + Q[v] + bagg + ef_e @ W1c).
// PQ fp16 [N][512]; output bf16 hi/lo planes [N][256] (+ps).

__global__ __launch_bounds__(256) void aggregate_kernel(
    const __half* __restrict__ PQ, const float* __restrict__ bagg,
    const __half* __restrict__ ef8, const int* __restrict__ offs,
    const int* __restrict__ csr_src, const float* __restrict__ W1c,
    unsigned short* __restrict__ Hagg, long ps, int n) {
    const int wave = threadIdx.x >> 6;
    const int lane = threadIdx.x & 63;
    const int node = blockIdx.x * 4 + wave;
    if (node >= n) return;
    const int hw = lane >> 5;
    const int sl = lane & 31;
    const int ch = sl * 8;

    float wc[6][8];
#pragma unroll
    for (int k = 0; k < 6; ++k) {
        float4 w0 = *reinterpret_cast<const float4*>(W1c + k * HID + ch);
        float4 w1 = *reinterpret_cast<const float4*>(W1c + k * HID + ch + 4);
        wc[k][0] = w0.x; wc[k][1] = w0.y; wc[k][2] = w0.z; wc[k][3] = w0.w;
        wc[k][4] = w1.x; wc[k][5] = w1.y; wc[k][6] = w1.z; wc[k][7] = w1.w;
    }
    float qb[8];
    {
        int4 r = *reinterpret_cast<const int4*>(PQ + (size_t)node * 512 + 256 + ch);
        unpack_h8(r, qb);
        float4 b0 = *reinterpret_cast<const float4*>(bagg + ch);
        float4 b1 = *reinterpret_cast<const float4*>(bagg + ch + 4);
        qb[0] += b0.x; qb[1] += b0.y; qb[2] += b0.z; qb[3] += b0.w;
        qb[4] += b1.x; qb[5] += b1.y; qb[6] += b1.z; qb[7] += b1.w;
    }
    float acc[8] = {0.f, 0.f, 0.f, 0.f, 0.f, 0.f, 0.f, 0.f};

    const int beg = offs[node];
    const int end = offs[node + 1];
#pragma unroll 2
    for (int j = beg + hw; j < end; j += 2) {
        int s = csr_src[j];
        int4 praw = *reinterpret_cast<const int4*>(PQ + (size_t)s * 512 + ch);
        int4 eraw = *reinterpret_cast<const int4*>(ef8 + (size_t)j * 8);
        float p[8], e[8];
        unpack_h8(praw, p);
        unpack_h8(eraw, e);
#pragma unroll
        for (int i = 0; i < 8; ++i) {
            float h = p[i] + qb[i];
            h = fmaf(e[0], wc[0][i], h);
            h = fmaf(e[1], wc[1][i], h);
            h = fmaf(e[2], wc[2][i], h);
            h = fmaf(e[3], wc[3][i], h);
            h = fmaf(e[4], wc[4][i], h);
            h = fmaf(e[5], wc[5][i], h);
            acc[i] += fmaxf(h, 0.f);
        }
    }
    float tot[8];
#pragma unroll
    for (int i = 0; i < 8; ++i) tot[i] = acc[i] + __shfl_down(acc[i], 32, 64);
    if (hw == 0) {
        unsigned short hh[8], hl[8];
#pragma unroll
        for (int i = 0; i < 8; ++i) {
            hh[i] = bf_rne(tot[i]);
            float fh = __uint_as_float((unsigned)hh[i] << 16);
            hl[i] = bf_rne(tot[i] - fh);
        }
        int4 ph, pl;
        ph.x = (int)(hh[0] | ((unsigned)hh[1] << 16));
        ph.y = (int)(hh[2] | ((unsigned)hh[3] << 16));
        ph.z = (int)(hh[4] | ((unsigned)hh[5] << 16));
        ph.w = (int)(hh[6] | ((unsigned)hh[7] << 16));
        pl.x = (int)(hl[0] | ((unsigned)hl[1] << 16));
        pl.y = (int)(hl[2] | ((unsigned)hl[3] << 16));
        pl.z = (int)(hl[4] | ((unsigned)hl[5] << 16));
        pl.w = (int)(hl[6] | ((unsigned)hl[7] << 16));
        *reinterpret_cast<int4*>(&Hagg[(size_t)node * HID + ch]) = ph;
        *reinterpret_cast<int4*>(&Hagg[ps + (size_t)node * HID + ch]) = pl;
    }
}

// ------------------------------- readout -----------------------------------

__global__ __launch_bounds__(256) void readout_dot_kernel(
    const __half* __restrict__ h2, const float* __restrict__ w3,
    float* __restrict__ accum, int n) {
    const int wave = threadIdx.x >> 6;
    const int lane = threadIdx.x & 63;
    const int nwaves = gridDim.x * 4;
    const int wid = blockIdx.x * 4 + wave;
    const float2 w = *reinterpret_cast<const float2*>(w3 + lane * 2);
    float local = 0.f;
    for (int node = wid; node < n; node += nwaves) {
        __half2 v = *reinterpret_cast<const __half2*>(h2 + (size_t)node * 128 + lane * 2);
        float2 vf = __half22float2(v);
        local = fmaf(vf.x, w.x, local);
        local = fmaf(vf.y, w.y, local);
    }
    for (int off = 32; off > 0; off >>= 1) local += __shfl_down(local, off, 64);
    if (lane == 0) atomicAdd(accum, local);
}

__global__ void finalize_kernel(const float* __restrict__ accum, const float* __restrict__ b3,
                                float* __restrict__ out, float inv_n) {
    out[0] = accum[0] * inv_n + b3[0];
}

// ------------------------------- driver ------------------------------------

extern "C" void kernel_launch(void* const* d_in, const int* in_sizes, int n_in,
                              void* d_out, int out_size, void* d_ws, size_t ws_size,
                              hipStream_t stream) {
    const float* atom   = (const float*)d_in[0];
    const int*   eidx   = (const int*)d_in[1];
    const float* ef     = (const float*)d_in[2];
    const float* emb_w  = (const float*)d_in[3];
    const float* emb_b  = (const float*)d_in[4];
    const float* msg_w1 = (const float*)d_in[5];
    const float* msg_b1 = (const float*)d_in[6];
    const float* msg_w2 = (const float*)d_in[7];
    const float* msg_b2 = (const float*)d_in[8];
    const float* upd_w1 = (const float*)d_in[9];
    const float* upd_b1 = (const float*)d_in[10];
    const float* upd_w2 = (const float*)d_in[11];
    const float* upd_b2 = (const float*)d_in[12];
    const float* r_w1   = (const float*)d_in[13];
    const float* r_b1   = (const float*)d_in[14];
    const float* r_w2   = (const float*)d_in[15];
    const float* r_b2   = (const float*)d_in[16];
    const float* r_w3   = (const float*)d_in[17];
    const float* r_b3   = (const float*)d_in[18];

    const int N = in_sizes[0] / 62;
    const int E = in_sizes[1] / 2;
    const int L = in_sizes[5] / (518 * 256);
    const int* src = eidx;
    const int* dst = eidx + E;

    char* wp = (char*)d_ws;
    auto alloc = [&](size_t bytes) -> void* {
        void* p = (void*)wp;
        wp += (bytes + 255) & ~(size_t)255;
        return p;
    };
    int*   deg     = (int*)alloc((size_t)N * 4);
    int*   cursor  = (int*)alloc((size_t)N * 4);
    float* accum   = (float*)alloc(256);
    size_t zero_bytes = (size_t)((char*)accum - (char*)d_ws) + 256;
    float* degf    = (float*)alloc((size_t)N * 4);
    int*   offs    = (int*)alloc((size_t)(N + 1) * 4);
    int*   csr_src = (int*)alloc((size_t)E * 4);
    __half* ef8    = (__half*)alloc((size_t)E * 8 * 2);

    const int EMB_P = 256 * 64, PQ_P = 512 * 256, SQ_P = 256 * 256, R2_P = 128 * 256;
    unsigned short* w_emb = (unsigned short*)alloc((size_t)EMB_P * 2 * 2);
    unsigned short* w_xu0 = (unsigned short*)alloc((size_t)SQ_P * 2 * 2);
    unsigned short* w_r2  = (unsigned short*)alloc((size_t)R2_P * 2 * 2);
    unsigned short* wF    = (unsigned short*)alloc((size_t)SQ_P * 2 * 2);
    unsigned short *wPQ[6], *wM2_[6], *wM3_[6];
    for (int l = 0; l < L; ++l) {
        wPQ[l]  = (unsigned short*)alloc((size_t)PQ_P * 2 * 2);
        wM2_[l] = (unsigned short*)alloc((size_t)SQ_P * 2 * 2);
        wM3_[l] = (unsigned short*)alloc((size_t)SQ_P * 2 * 2);
    }
    unsigned short* fb[22];
    for (int i = 0; i < 22; ++i)
        fb[i] = (unsigned short*)alloc((size_t)SQ_P * 2 * 2);
    float* pscr = (float*)alloc((size_t)22 * 65536 * 4);
    float* bvec = (float*)alloc((size_t)19 * 256 * 4);

    const long APS = (long)N * HID;   // activation plane stride (elements)
    unsigned short* atomP = (unsigned short*)alloc((size_t)N * 64 * 2 * 2);
    unsigned short* bufX0 = (unsigned short*)alloc((size_t)APS * 2 * 2);
    unsigned short* bufX1 = (unsigned short*)alloc((size_t)APS * 2 * 2);
    unsigned short* HaggP = (unsigned short*)alloc((size_t)APS * 2 * 2);
    __half* PQh   = (__half*)alloc((size_t)N * 512 * 2);  // also h2 [N,128]

    hipMemsetAsync(d_ws, 0, zero_bytes, stream);

    // ---- CSR build ----
    hist_kernel<<<(E + 255) / 256, 256, 0, stream>>>(dst, deg, E);
    scan_kernel<<<1, 256, 0, stream>>>(deg, offs, degf, N);
    scatter_kernel<<<(E + 255) / 256, 256, 0, stream>>>(src, dst, offs, cursor,
                                                        csr_src, ef, ef8, E);
    // ---- atom -> planes ----
    act_convert<<<(N * 8 + 255) / 256, 256, 0, stream>>>(atom, atomP, (long)N * 64,
                                                         N, 62, 64);

    // ---- convert pass 1: direct-use weights + fold B-operands ----
    CTab ct1;
    int nd = 0, tiles = 0;
    auto addDesc = [&](CTab& ct, const float* s, unsigned short* dh, unsigned short* dl,
                       int Kreal, int Kpad, int srcN) {
        ct.d[nd] = {s, dh, dl, Kreal, Kpad, srcN, tiles};
        tiles += (Kpad / 32) * (srcN / 64);
        ++nd;
    };
    addDesc(ct1, emb_w, w_emb, w_emb + EMB_P, 62, 64, 256);
    addDesc(ct1, msg_w1, wPQ[0], wPQ[0] + PQ_P, 256, 256, 256);
    addDesc(ct1, msg_w1 + 256 * 256, wPQ[0] + SQ_P, wPQ[0] + PQ_P + SQ_P, 256, 256, 256);
    addDesc(ct1, upd_w1, w_xu0, w_xu0 + SQ_P, 256, 256, 256);
    addDesc(ct1, r_w2, w_r2, w_r2 + R2_P, 256, 256, 128);
    for (int l = 1; l < L; ++l) {
        addDesc(ct1, msg_w1 + (size_t)l * 518 * 256,             fb[l - 1],  fb[l - 1] + SQ_P, 256, 256, 256);
        addDesc(ct1, msg_w1 + (size_t)l * 518 * 256 + 256 * 256, fb[4 + l],  fb[4 + l] + SQ_P, 256, 256, 256);
        addDesc(ct1, upd_w1 + (size_t)l * 512 * 256,             fb[9 + l],  fb[9 + l] + SQ_P, 256, 256, 256);
    }
    for (int l = 0; l < L; ++l)
        addDesc(ct1, upd_w1 + (size_t)l * 512 * 256 + 256 * 256, fb[15 + l], fb[15 + l] + SQ_P, 256, 256, 256);
    addDesc(ct1, r_w1, fb[21], fb[21] + SQ_P, 256, 256, 256);
    ct1.nd = nd;
    convert_weights<<<tiles, 256, 0, stream>>>(ct1);

    // ---- fold GEMMs on matrix cores ----
    FTab ft;
    for (int l = 1; l < L; ++l) {
        const float* U2p = upd_w2 + (size_t)(l - 1) * SQ_P;
        ft.d[l - 1] = {U2p, fb[l - 1], fb[l - 1] + SQ_P, pscr + (size_t)(l - 1) * 65536};
        ft.d[4 + l] = {U2p, fb[4 + l], fb[4 + l] + SQ_P, pscr + (size_t)(4 + l) * 65536};
        ft.d[9 + l] = {U2p, fb[9 + l], fb[9 + l] + SQ_P, pscr + (size_t)(9 + l) * 65536};
    }
    for (int l = 0; l < L; ++l)
        ft.d[15 + l] = {msg_w2 + (size_t)l * SQ_P, fb[15 + l], fb[15 + l] + SQ_P,
                        pscr + (size_t)(15 + l) * 65536};
    ft.d[21] = {upd_w2 + (size_t)5 * SQ_P, fb[21], fb[21] + SQ_P, pscr + (size_t)21 * 65536};
    fold_gemm<<<22 * 16, 256, 0, stream>>>(ft);

    // ---- convert pass 2: folded products ----
    CTab ct2;
    nd = 0; tiles = 0;
    for (int l = 1; l < L; ++l) {
        addDesc(ct2, pscr + (size_t)(l - 1) * 65536, wPQ[l], wPQ[l] + PQ_P, 256, 256, 256);
        addDesc(ct2, pscr + (size_t)(4 + l) * 65536, wPQ[l] + SQ_P, wPQ[l] + PQ_P + SQ_P, 256, 256, 256);
        addDesc(ct2, pscr + (size_t)(9 + l) * 65536, wM2_[l], wM2_[l] + SQ_P, 256, 256, 256);
    }
    for (int l = 0; l < L; ++l)
        addDesc(ct2, pscr + (size_t)(15 + l) * 65536, wM3_[l], wM3_[l] + SQ_P, 256, 256, 256);
    addDesc(ct2, pscr + (size_t)21 * 65536, wF, wF + SQ_P, 256, 256, 256);
    ct2.nd = nd;
    convert_weights<<<tiles, 256, 0, stream>>>(ct2);

    // ---- folded bias vectors ----
    BTab bt;
    for (int l = 0; l < L; ++l) {
        const float* ub2p = (l > 0) ? upd_b2 + (size_t)(l - 1) * 256 : nullptr;
        bt.d[l] = {bvec + (size_t)l * 256, msg_b1 + (size_t)l * 256,
                   ub2p, msg_w1 + (size_t)l * 518 * 256,
                   ub2p, msg_w1 + (size_t)l * 518 * 256 + 256 * 256};
        bt.d[6 + l] = {bvec + (size_t)(6 + l) * 256, upd_b1 + (size_t)l * 256,
                       ub2p, upd_w1 + (size_t)l * 512 * 256, nullptr, nullptr};
        bt.d[12 + l] = {bvec + (size_t)(12 + l) * 256, nullptr,
                        msg_b2 + (size_t)l * 256, upd_w1 + (size_t)l * 512 * 256 + 256 * 256,
                        nullptr, nullptr};
    }
    bt.d[18] = {bvec + (size_t)18 * 256, r_b1, upd_b2 + (size_t)5 * 256, r_w1,
                nullptr, nullptr};
    biasvec_kernel<<<19, 256, 0, stream>>>(bt);

    const int mblk = (N + 63) / 64;
    dim3 blk(256);

    // embed: U0 = atom @ emb_w + emb_b  (planes out)
    mfma_gemm<<<dim3(mblk, 2), blk, 0, stream>>>(
        atomP, 64, (long)N * 64, w_emb, EMB_P, 64,
        nullptr, 0, 0, nullptr, 0, 0,
        emb_b, nullptr, nullptr, bufX0, APS, nullptr, N, HID, 0);

    unsigned short* U_prev = bufX0;
    unsigned short* U_next = bufX1;
    for (int l = 0; l < L; ++l) {
        const float* w1c = msg_w1 + (size_t)l * 518 * 256 + 512 * 256;
        const unsigned short* xu = (l == 0) ? w_xu0 : wM2_[l];

        // PQ = U_prev @ [M1a | M1b]  (fp16 out)
        mfma_gemm<<<dim3(mblk, 4), blk, 0, stream>>>(
            U_prev, HID, APS, wPQ[l], PQ_P, HID,
            nullptr, 0, 0, nullptr, 0, 0,
            nullptr, nullptr, nullptr, nullptr, 0, PQh, N, 512, 0);
        // Hagg planes
        aggregate_kernel<<<(N + 3) / 4, blk, 0, stream>>>(
            PQh, bvec + (size_t)l * 256, ef8, offs, csr_src, w1c, HaggP, APS, N);
        // U = relu(U_prev@M2 + Hagg@M3 + cb_u + deg.*db)  (planes out)
        mfma_gemm<<<dim3(mblk, 2), blk, 0, stream>>>(
            U_prev, HID, APS, xu, SQ_P, HID,
            HaggP, HID, APS, wM3_[l], SQ_P, HID,
            bvec + (size_t)(6 + l) * 256, bvec + (size_t)(12 + l) * 256, degf,
            U_next, APS, nullptr, N, HID, 1);
        unsigned short* t = U_prev; U_prev = U_next; U_next = t;
    }

    // readout: h1 = relu(U5@F + cb_r) planes; h2 = relu(h1@r_w2 + r_b2) fp16
    mfma_gemm<<<dim3(mblk, 2), blk, 0, stream>>>(
        U_prev, HID, APS, wF, SQ_P, HID,
        nullptr, 0, 0, nullptr, 0, 0,
        bvec + (size_t)18 * 256, nullptr, nullptr, U_next, APS, nullptr, N, HID, 1);
    mfma_gemm<<<dim3(mblk, 1), blk, 0, stream>>>(
        U_next, HID, APS, w_r2, R2_P, HID,
        nullptr, 0, 0, nullptr, 0, 0,
        r_b2, nullptr, nullptr, nullptr, 0, PQh, N, 128, 1);
    readout_dot_kernel<<<256, blk, 0, stream>>>(PQh, r_w3, accum, N);
    finalize_kernel<<<1, 1, 0, stream>>>(accum, r_b3, (float*)d_out, 1.0f / (float)N);
}

// Round 6
// 565.763 us; speedup vs baseline: 1.1151x; 1.1151x over previous
//
#include <hip/hip_runtime.h>
#include <hip/hip_bf16.h>
#include <hip/hip_fp16.h>

// ---------------------------------------------------------------------------
// MPNN binding-affinity predictor. R6:
//  - native fp16 MFMA (f32 accum): 1 MFMA per tile (was 3-MFMA bf16 split),
//    single-plane fp16 weights/activations (fp16 products exact in fp32 acc)
//  - PQR fused GEMM (Nc=768): emits P|Q|R, U-GEMM single-pass + addend
//  - templated tile width (128 for PQR, 64 for Nc<=256 -> 2x block count)
//  - aggregate: prefetch-pipelined gather
// ---------------------------------------------------------------------------

#define HID 256

typedef _Float16 h8 __attribute__((ext_vector_type(8)));
typedef float f32x4 __attribute__((ext_vector_type(4)));

__device__ __forceinline__ void unpack_h8(const int4& r, float* f) {
    const __half2* h = reinterpret_cast<const __half2*>(&r);
#pragma unroll
    for (int k = 0; k < 4; ++k) {
        float2 t = __half22float2(h[k]);
        f[2 * k] = t.x;
        f[2 * k + 1] = t.y;
    }
}

// async global -> LDS 16B DMA; dest wave-uniform, lane i lands at dest+16*i
__device__ __forceinline__ void gld16(const void* g, void* l) {
    __builtin_amdgcn_global_load_lds(
        (const __attribute__((address_space(1))) void*)g,
        (__attribute__((address_space(3))) void*)l, 16, 0, 0);
}

// XOR swizzle of 16B k-segments per row; fragment reads <=2-way (free)
__device__ __forceinline__ int swz(int row) { return (row + (row >> 2)) & 3; }

// ------------------------------ CSR build ----------------------------------

__global__ void hist_kernel(const int* __restrict__ dst, int* __restrict__ deg, int E) {
    int i = blockIdx.x * blockDim.x + threadIdx.x;
    if (i < E) atomicAdd(&deg[dst[i]], 1);
}

__global__ __launch_bounds__(256) void scan_kernel(
    const int* __restrict__ deg, int* __restrict__ offs, float* __restrict__ degf, int n) {
    __shared__ int ws[4];
    const int t = threadIdx.x;
    const int lane = t & 63;
    const int w = t >> 6;
    const int per = (n + 255) / 256;
    const int s = t * per;
    const int e = min(s + per, n);
    int sum = 0;
    for (int i = s; i < e; ++i) sum += deg[i];
    int v = sum;
#pragma unroll
    for (int off = 1; off < 64; off <<= 1) {
        int u = __shfl_up(v, off, 64);
        if (lane >= off) v += u;
    }
    if (lane == 63) ws[w] = v;
    __syncthreads();
    if (t == 0) {
        int c = 0;
#pragma unroll
        for (int i = 0; i < 4; ++i) { int x = ws[i]; ws[i] = c; c += x; }
    }
    __syncthreads();
    int run = ws[w] + v - sum;
    for (int i = s; i < e; ++i) {
        int d = deg[i];
        offs[i] = run;
        degf[i] = (float)d;
        run += d;
    }
    if (e == n) offs[n] = run;
}

__global__ void scatter_kernel(const int* __restrict__ src, const int* __restrict__ dst,
                               const int* __restrict__ offs, int* __restrict__ cursor,
                               int* __restrict__ csr_src, const float* __restrict__ ef,
                               __half* __restrict__ ef8, int E) {
    int i = blockIdx.x * blockDim.x + threadIdx.x;
    if (i < E) {
        int d = dst[i];
        int pos = atomicAdd(&cursor[d], 1);
        int idx = offs[d] + pos;
        csr_src[idx] = src[i];
        const float* s6 = ef + (size_t)i * 6;
        unsigned short h[8];
#pragma unroll
        for (int j = 0; j < 6; ++j) h[j] = __half_as_ushort(__float2half_rn(s6[j]));
        h[6] = 0; h[7] = 0;
        int4 pk;
        pk.x = (int)(h[0] | ((unsigned)h[1] << 16));
        pk.y = (int)(h[2] | ((unsigned)h[3] << 16));
        pk.z = (int)(h[4] | ((unsigned)h[5] << 16));
        pk.w = (int)(h[6] | ((unsigned)h[7] << 16));
        *reinterpret_cast<int4*>(ef8 + (size_t)idx * 8) = pk;
    }
}

// ----------------------- folded bias vectors -------------------------------

struct BDesc { float* out; const float* base; const float* v1; const float* B1;
               const float* v2; const float* B2; };
struct BTab { BDesc d[19]; };

__global__ __launch_bounds__(256) void biasvec_kernel(BTab tab) {
    const BDesc d = tab.d[blockIdx.x];
    const int j = threadIdx.x;
    float acc = d.base ? d.base[j] : 0.f;
    if (d.v1)
        for (int k = 0; k < 256; ++k) acc = fmaf(d.v1[k], d.B1[(size_t)k * 256 + j], acc);
    if (d.v2)
        for (int k = 0; k < 256; ++k) acc = fmaf(d.v2[k], d.B2[(size_t)k * 256 + j], acc);
    d.out[j] = acc;
}

// ------------------------ weight convert -----------------------------------
// src [Kreal, srcN] fp32 row-major -> dst [srcN][Kpad] fp16 (transposed).

struct CDesc {
    const float* src;
    __half* dst;
    int Kreal, Kpad, srcN, tile0;
};
struct CTab {
    CDesc d[32];
    int nd;
};

__global__ __launch_bounds__(256) void convert_weights(CTab tab) {
    const int bid = blockIdx.x;
    int idx = 0;
    for (int i = 1; i < tab.nd; ++i)
        if (tab.d[i].tile0 <= bid) idx = i;
    const CDesc d = tab.d[idx];
    const int q = bid - d.tile0;
    const int ntN = d.srcN >> 6;
    const int kb = (q / ntN) * 32;
    const int nb = (q % ntN) * 64;
    const int n = nb + (threadIdx.x & 63);
    const int k0 = kb + (threadIdx.x >> 6) * 8;
    h8 v;
#pragma unroll
    for (int j = 0; j < 8; ++j) {
        int k = k0 + j;
        v[j] = (_Float16)((k < d.Kreal) ? d.src[(size_t)k * d.srcN + n] : 0.f);
    }
    *reinterpret_cast<h8*>(&d.dst[(size_t)n * d.Kpad + k0]) = v;
}

// ------------------- activation fp32 -> fp16 (pad cols) --------------------

__global__ __launch_bounds__(256) void act_convert(
    const float* __restrict__ src, __half* __restrict__ dst,
    int rows, int scols, int dcols) {
    const int nseg = dcols >> 3;
    int t = blockIdx.x * blockDim.x + threadIdx.x;
    if (t >= rows * nseg) return;
    int r = t / nseg, seg = t - r * nseg;
    h8 v;
#pragma unroll
    for (int j = 0; j < 8; ++j) {
        int c = seg * 8 + j;
        v[j] = (_Float16)((c < scols) ? src[(size_t)r * scols + c] : 0.f);
    }
    *reinterpret_cast<h8*>(&dst[(size_t)r * dcols + seg * 8]) = v;
}

// ------------------- batched fold GEMM (fp16 MFMA) -------------------------
// C[256,256] fp32 = A[256,256] fp32 (cvt fp16 in-kernel) @ B (fp16 [n][k]).

#define ASTR 40

struct FDesc { const float* A; const __half* B; float* C; };
struct FTab { FDesc d[22]; };

__global__ __launch_bounds__(256) void fold_gemm(FTab tab) {
    const FDesc dd = tab.d[blockIdx.x >> 4];
    const int t4 = blockIdx.x & 15;
    const int rowBase = (t4 >> 2) * 64;
    const int colBase = (t4 & 3) * 64;

    __shared__ __align__(16) _Float16 Ah[64 * ASTR];
    __shared__ __align__(16) _Float16 Bh[64 * ASTR];

    const int tid = threadIdx.x;
    const int lane = tid & 63;
    const int wave = tid >> 6;
    const int waveM = (wave >> 1) * 32;
    const int waveN = (wave & 1) * 32;
    const int m0 = lane & 15;
    const int quad = lane >> 4;
    const int sr = tid >> 2;
    const int sseg = tid & 3;

    const f32x4 z = {0.f, 0.f, 0.f, 0.f};
    f32x4 acc[2][2] = {{z, z}, {z, z}};

    for (int kb = 0; kb < 256; kb += 32) {
        {
            const float* Ap = dd.A + (size_t)(rowBase + sr) * 256 + kb + sseg * 8;
            float4 u0 = *reinterpret_cast<const float4*>(Ap);
            float4 u1 = *reinterpret_cast<const float4*>(Ap + 4);
            h8 v;
            v[0] = (_Float16)u0.x; v[1] = (_Float16)u0.y;
            v[2] = (_Float16)u0.z; v[3] = (_Float16)u0.w;
            v[4] = (_Float16)u1.x; v[5] = (_Float16)u1.y;
            v[6] = (_Float16)u1.z; v[7] = (_Float16)u1.w;
            *reinterpret_cast<h8*>(&Ah[sr * ASTR + sseg * 8]) = v;
        }
        {
            size_t off = (size_t)(colBase + sr) * 256 + kb + sseg * 8;
            *reinterpret_cast<int4*>(&Bh[sr * ASTR + sseg * 8]) =
                *reinterpret_cast<const int4*>(&dd.B[off]);
        }
        __syncthreads();

        const h8 a0 = *reinterpret_cast<const h8*>(&Ah[(waveM + m0) * ASTR + quad * 8]);
        const h8 a1 = *reinterpret_cast<const h8*>(&Ah[(waveM + 16 + m0) * ASTR + quad * 8]);
        const h8 b0 = *reinterpret_cast<const h8*>(&Bh[(waveN + m0) * ASTR + quad * 8]);
        const h8 b1 = *reinterpret_cast<const h8*>(&Bh[(waveN + 16 + m0) * ASTR + quad * 8]);

        acc[0][0] = __builtin_amdgcn_mfma_f32_16x16x32_f16(a0, b0, acc[0][0], 0, 0, 0);
        acc[0][1] = __builtin_amdgcn_mfma_f32_16x16x32_f16(a0, b1, acc[0][1], 0, 0, 0);
        acc[1][0] = __builtin_amdgcn_mfma_f32_16x16x32_f16(a1, b0, acc[1][0], 0, 0, 0);
        acc[1][1] = __builtin_amdgcn_mfma_f32_16x16x32_f16(a1, b1, acc[1][1], 0, 0, 0);

        __syncthreads();
    }

#pragma unroll
    for (int tm = 0; tm < 2; ++tm)
#pragma unroll
        for (int reg = 0; reg < 4; ++reg) {
            int row = rowBase + waveM + tm * 16 + quad * 4 + reg;
#pragma unroll
            for (int tn = 0; tn < 2; ++tn) {
                int col = colBase + waveN + tn * 16 + m0;
                dd.C[(size_t)row * 256 + col] = acc[tm][tn][reg];
            }
        }
}

// ------------------------------ MFMA GEMM ----------------------------------
// C = act( A@W + bias + rowscale.*bias2 + addend ), all fp16 in / fp16 out,
// fp32 accumulate. A [M][lda] fp16, W [Nc][K] fp16. Tile 64 x (TN*32), BK=32,
// 4 waves 2x2 (wave tile 32 x TN*16). Pure global_load_lds staging,
// XOR-swizzled LDS.

template <int TN>
__global__ __launch_bounds__(256) void mfma_gemm(
    const __half* __restrict__ A, int lda,
    const __half* __restrict__ W, int K,
    const float* __restrict__ bias, const float* __restrict__ bias2,
    const float* __restrict__ rowscale,
    const __half* __restrict__ addend, int astride,
    __half* __restrict__ C, int M, int Nc, int do_relu) {
    // A at [0, 4K); B at [4K, 4K + TN*2K)
    __shared__ __align__(16) unsigned char lds[4096 + TN * 2048];

    const int tid = threadIdx.x;
    const int lane = tid & 63;
    const int wave = tid >> 6;
    const int m0 = lane & 15;
    const int quad = lane >> 4;
    const int waveM = (wave >> 1) * 32;
    const int waveN = (wave & 1) * (TN * 16);
    const int rowBase = blockIdx.x * 64;
    const int colBase = blockIdx.y * (TN * 32);

    const int sa_r = tid >> 2;
    const int sa_ks = (tid & 3) ^ swz(sa_r);
    const int sa_row = min(rowBase + sa_r, M - 1);
    const int sb_r1 = sa_r + 64;
    const int sb_ks1 = (tid & 3) ^ swz(sb_r1);

    int aoff[2], boff[TN];
#pragma unroll
    for (int tm = 0; tm < 2; ++tm) {
        int r = waveM + tm * 16 + m0;
        aoff[tm] = ((r << 2) + (quad ^ swz(r))) << 4;
    }
#pragma unroll
    for (int tn = 0; tn < TN; ++tn) {
        int r = waveN + tn * 16 + m0;
        boff[tn] = 4096 + (((r << 2) + (quad ^ swz(r))) << 4);
    }

    const f32x4 z = {0.f, 0.f, 0.f, 0.f};
    f32x4 acc[2][TN];
#pragma unroll
    for (int tm = 0; tm < 2; ++tm)
#pragma unroll
        for (int tn = 0; tn < TN; ++tn) acc[tm][tn] = z;

    const __half* ga = A + (size_t)sa_row * lda + sa_ks * 8;
    const __half* gb0 = W + (size_t)(colBase + sa_r) * K + sa_ks * 8;
    const __half* gb1 = W + (size_t)(colBase + sb_r1) * K + sb_ks1 * 8;

    for (int kb = 0; kb < K; kb += 32) {
        gld16(ga + kb, lds + wave * 1024);
        gld16(gb0 + kb, lds + 4096 + wave * 1024);
        if constexpr (TN == 4) gld16(gb1 + kb, lds + 8192 + wave * 1024);
        __syncthreads();

        h8 ah[2], bh[TN];
#pragma unroll
        for (int tm = 0; tm < 2; ++tm)
            ah[tm] = *reinterpret_cast<const h8*>(lds + aoff[tm]);
#pragma unroll
        for (int tn = 0; tn < TN; ++tn)
            bh[tn] = *reinterpret_cast<const h8*>(lds + boff[tn]);
#pragma unroll
        for (int tm = 0; tm < 2; ++tm)
#pragma unroll
            for (int tn = 0; tn < TN; ++tn)
                acc[tm][tn] = __builtin_amdgcn_mfma_f32_16x16x32_f16(
                    ah[tm], bh[tn], acc[tm][tn], 0, 0, 0);
        __syncthreads();
    }

    // epilogue
    float cb[TN], db[TN];
    int col[TN];
#pragma unroll
    for (int tn = 0; tn < TN; ++tn) {
        col[tn] = colBase + waveN + tn * 16 + m0;
        cb[tn] = bias ? bias[col[tn]] : 0.f;
        db[tn] = bias2 ? bias2[col[tn]] : 0.f;
    }
#pragma unroll
    for (int tm = 0; tm < 2; ++tm) {
#pragma unroll
        for (int reg = 0; reg < 4; ++reg) {
            int row = rowBase + waveM + tm * 16 + quad * 4 + reg;
            if (row >= M) continue;
            float rs = rowscale ? rowscale[row] : 0.0f;
#pragma unroll
            for (int tn = 0; tn < TN; ++tn) {
                float v = acc[tm][tn][reg] + cb[tn] + rs * db[tn];
                if (addend)
                    v += __half2float(addend[(size_t)row * astride + col[tn]]);
                if (do_relu) v = fmaxf(v, 0.f);
                C[(size_t)row * Nc + col[tn]] = __float2half_rn(v);
            }
        }
    }
}

// --------------------------- edge aggregation ------------------------------
// Hagg[v] = sum_{e=(s,v)} relu(P[s] + Q[v] + bagg + ef_e @ W1c).
// PQR fp16 [N][768] (P=0..255, Q=256..511). Prefetch-pipelined gather.

__global__ __launch_bounds__(256) void aggregate_kernel(
    const __half* __restrict__ PQ, const float* __restrict__ bagg,
    const __half* __restrict__ ef8, const int* __restrict__ offs,
    const int* __restrict__ csr_src, const float* __restrict__ W1c,
    __half* __restrict__ Hagg, int n) {
    const int wave = threadIdx.x >> 6;
    const int lane = threadIdx.x & 63;
    const int node = blockIdx.x * 4 + wave;
    if (node >= n) return;
    const int hw = lane >> 5;
    const int sl = lane & 31;
    const int ch = sl * 8;

    float wc[6][8];
#pragma unroll
    for (int k = 0; k < 6; ++k) {
        float4 w0 = *reinterpret_cast<const float4*>(W1c + k * HID + ch);
        float4 w1 = *reinterpret_cast<const float4*>(W1c + k * HID + ch + 4);
        wc[k][0] = w0.x; wc[k][1] = w0.y; wc[k][2] = w0.z; wc[k][3] = w0.w;
        wc[k][4] = w1.x; wc[k][5] = w1.y; wc[k][6] = w1.z; wc[k][7] = w1.w;
    }
    float qb[8];
    {
        int4 r = *reinterpret_cast<const int4*>(PQ + (size_t)node * 768 + 256 + ch);
        unpack_h8(r, qb);
        float4 b0 = *reinterpret_cast<const float4*>(bagg + ch);
        float4 b1 = *reinterpret_cast<const float4*>(bagg + ch + 4);
        qb[0] += b0.x; qb[1] += b0.y; qb[2] += b0.z; qb[3] += b0.w;
        qb[4] += b1.x; qb[5] += b1.y; qb[6] += b1.z; qb[7] += b1.w;
    }
    float acc[8] = {0.f, 0.f, 0.f, 0.f, 0.f, 0.f, 0.f, 0.f};

    const int beg = offs[node];
    const int end = offs[node + 1];
    int j = beg + hw;
    int4 praw = {0, 0, 0, 0}, eraw = {0, 0, 0, 0};
    if (j < end) {
        int s = csr_src[j];
        eraw = *reinterpret_cast<const int4*>(ef8 + (size_t)j * 8);
        praw = *reinterpret_cast<const int4*>(PQ + (size_t)s * 768 + ch);
    }
    while (j < end) {
        int jn = j + 2;
        int4 prn = praw, ern = eraw;
        if (jn < end) {
            int sn = csr_src[jn];
            ern = *reinterpret_cast<const int4*>(ef8 + (size_t)jn * 8);
            prn = *reinterpret_cast<const int4*>(PQ + (size_t)sn * 768 + ch);
        }
        float p[8], e[8];
        unpack_h8(praw, p);
        unpack_h8(eraw, e);
#pragma unroll
        for (int i = 0; i < 8; ++i) {
            float h = p[i] + qb[i];
            h = fmaf(e[0], wc[0][i], h);
            h = fmaf(e[1], wc[1][i], h);
            h = fmaf(e[2], wc[2][i], h);
            h = fmaf(e[3], wc[3][i], h);
            h = fmaf(e[4], wc[4][i], h);
            h = fmaf(e[5], wc[5][i], h);
            acc[i] += fmaxf(h, 0.f);
        }
        j = jn;
        praw = prn;
        eraw = ern;
    }
    unsigned short hs[8];
#pragma unroll
    for (int i = 0; i < 8; ++i) {
        float tot = acc[i] + __shfl_down(acc[i], 32, 64);
        hs[i] = __half_as_ushort(__float2half_rn(tot));
    }
    if (hw == 0) {
        int4 pk;
        pk.x = (int)(hs[0] | ((unsigned)hs[1] << 16));
        pk.y = (int)(hs[2] | ((unsigned)hs[3] << 16));
        pk.z = (int)(hs[4] | ((unsigned)hs[5] << 16));
        pk.w = (int)(hs[6] | ((unsigned)hs[7] << 16));
        *reinterpret_cast<int4*>(Hagg + (size_t)node * HID + ch) = pk;
    }
}

// ------------------------------- readout -----------------------------------

__global__ __launch_bounds__(256) void readout_dot_kernel(
    const __half* __restrict__ h2, const float* __restrict__ w3,
    float* __restrict__ accum, int n) {
    const int wave = threadIdx.x >> 6;
    const int lane = threadIdx.x & 63;
    const int nwaves = gridDim.x * 4;
    const int wid = blockIdx.x * 4 + wave;
    const float2 w = *reinterpret_cast<const float2*>(w3 + lane * 2);
    float local = 0.f;
    for (int node = wid; node < n; node += nwaves) {
        __half2 v = *reinterpret_cast<const __half2*>(h2 + (size_t)node * 128 + lane * 2);
        float2 vf = __half22float2(v);
        local = fmaf(vf.x, w.x, local);
        local = fmaf(vf.y, w.y, local);
    }
    for (int off = 32; off > 0; off >>= 1) local += __shfl_down(local, off, 64);
    if (lane == 0) atomicAdd(accum, local);
}

__global__ void finalize_kernel(const float* __restrict__ accum, const float* __restrict__ b3,
                                float* __restrict__ out, float inv_n) {
    out[0] = accum[0] * inv_n + b3[0];
}

// ------------------------------- driver ------------------------------------

extern "C" void kernel_launch(void* const* d_in, const int* in_sizes, int n_in,
                              void* d_out, int out_size, void* d_ws, size_t ws_size,
                              hipStream_t stream) {
    const float* atom   = (const float*)d_in[0];
    const int*   eidx   = (const int*)d_in[1];
    const float* ef     = (const float*)d_in[2];
    const float* emb_w  = (const float*)d_in[3];
    const float* emb_b  = (const float*)d_in[4];
    const float* msg_w1 = (const float*)d_in[5];
    const float* msg_b1 = (const float*)d_in[6];
    const float* msg_w2 = (const float*)d_in[7];
    const float* msg_b2 = (const float*)d_in[8];
    const float* upd_w1 = (const float*)d_in[9];
    const float* upd_b1 = (const float*)d_in[10];
    const float* upd_w2 = (const float*)d_in[11];
    const float* upd_b2 = (const float*)d_in[12];
    const float* r_w1   = (const float*)d_in[13];
    const float* r_b1   = (const float*)d_in[14];
    const float* r_w2   = (const float*)d_in[15];
    const float* r_b2   = (const float*)d_in[16];
    const float* r_w3   = (const float*)d_in[17];
    const float* r_b3   = (const float*)d_in[18];

    const int N = in_sizes[0] / 62;
    const int E = in_sizes[1] / 2;
    const int L = in_sizes[5] / (518 * 256);
    const int* src = eidx;
    const int* dst = eidx + E;

    char* wp = (char*)d_ws;
    auto alloc = [&](size_t bytes) -> void* {
        void* p = (void*)wp;
        wp += (bytes + 255) & ~(size_t)255;
        return p;
    };
    int*   deg     = (int*)alloc((size_t)N * 4);
    int*   cursor  = (int*)alloc((size_t)N * 4);
    float* accum   = (float*)alloc(256);
    size_t zero_bytes = (size_t)((char*)accum - (char*)d_ws) + 256;
    float* degf    = (float*)alloc((size_t)N * 4);
    int*   offs    = (int*)alloc((size_t)(N + 1) * 4);
    int*   csr_src = (int*)alloc((size_t)E * 4);
    __half* ef8    = (__half*)alloc((size_t)E * 8 * 2);

    const int SQ_P = 256 * 256;
    // fp16 weight planes
    __half* w_emb = (__half*)alloc((size_t)256 * 64 * 2);   // [256][64]
    __half* w_r2  = (__half*)alloc((size_t)128 * 256 * 2);  // [128][256]
    __half* wF    = (__half*)alloc((size_t)SQ_P * 2);       // [256][256]
    __half *wPQR[6], *wM3_[6];
    for (int l = 0; l < L; ++l) {
        wPQR[l] = (__half*)alloc((size_t)768 * 256 * 2);    // [768][256]: M1a|M1b|M2
        wM3_[l] = (__half*)alloc((size_t)SQ_P * 2);
    }
    __half* fb[22];
    for (int i = 0; i < 22; ++i) fb[i] = (__half*)alloc((size_t)SQ_P * 2);
    float* pscr = (float*)alloc((size_t)22 * 65536 * 4);
    float* bvec = (float*)alloc((size_t)19 * 256 * 4);

    __half* atomH = (__half*)alloc((size_t)N * 64 * 2);
    __half* bufX0 = (__half*)alloc((size_t)N * HID * 2);
    __half* bufX1 = (__half*)alloc((size_t)N * HID * 2);
    __half* PQR   = (__half*)alloc((size_t)N * 768 * 2);
    __half* HaggH = (__half*)alloc((size_t)N * HID * 2);  // also h2 [N,128]

    hipMemsetAsync(d_ws, 0, zero_bytes, stream);

    // ---- CSR build ----
    hist_kernel<<<(E + 255) / 256, 256, 0, stream>>>(dst, deg, E);
    scan_kernel<<<1, 256, 0, stream>>>(deg, offs, degf, N);
    scatter_kernel<<<(E + 255) / 256, 256, 0, stream>>>(src, dst, offs, cursor,
                                                        csr_src, ef, ef8, E);
    // ---- atom -> fp16 [N,64] ----
    act_convert<<<(N * 8 + 255) / 256, 256, 0, stream>>>(atom, atomH, N, 62, 64);

    // ---- convert pass 1: direct-use weights + fold B-operands ----
    // fb slots: 0..4 W1a_l(l=1..5), 5..9 W1b_l(l=1..5), 10..14 U1a_l(l=1..5),
    //           15..20 U1b_l(l=0..5), 21 r_w1
    CTab ct1;
    int nd = 0, tiles = 0;
    auto addDesc = [&](CTab& ct, const float* s, __half* dh, int Kreal, int Kpad,
                       int srcN) {
        ct.d[nd] = {s, dh, Kreal, Kpad, srcN, tiles};
        tiles += (Kpad / 32) * (srcN / 64);
        ++nd;
    };
    addDesc(ct1, emb_w, w_emb, 62, 64, 256);
    addDesc(ct1, msg_w1, wPQR[0], 256, 256, 256);                       // W1a_0
    addDesc(ct1, msg_w1 + 256 * 256, wPQR[0] + SQ_P, 256, 256, 256);    // W1b_0
    addDesc(ct1, upd_w1, wPQR[0] + 2 * SQ_P, 256, 256, 256);            // U1a_0
    addDesc(ct1, r_w2, w_r2, 256, 256, 128);
    for (int l = 1; l < L; ++l) {
        addDesc(ct1, msg_w1 + (size_t)l * 518 * 256,             fb[l - 1], 256, 256, 256);
        addDesc(ct1, msg_w1 + (size_t)l * 518 * 256 + 256 * 256, fb[4 + l], 256, 256, 256);
        addDesc(ct1, upd_w1 + (size_t)l * 512 * 256,             fb[9 + l], 256, 256, 256);
    }
    for (int l = 0; l < L; ++l)
        addDesc(ct1, upd_w1 + (size_t)l * 512 * 256 + 256 * 256, fb[15 + l], 256, 256, 256);
    addDesc(ct1, r_w1, fb[21], 256, 256, 256);
    ct1.nd = nd;
    convert_weights<<<tiles, 256, 0, stream>>>(ct1);

    // ---- fold GEMMs (fp16 MFMA) ----
    FTab ft;
    for (int l = 1; l < L; ++l) {
        const float* U2p = upd_w2 + (size_t)(l - 1) * SQ_P;
        ft.d[l - 1] = {U2p, fb[l - 1], pscr + (size_t)(l - 1) * 65536};
        ft.d[4 + l] = {U2p, fb[4 + l], pscr + (size_t)(4 + l) * 65536};
        ft.d[9 + l] = {U2p, fb[9 + l], pscr + (size_t)(9 + l) * 65536};
    }
    for (int l = 0; l < L; ++l)
        ft.d[15 + l] = {msg_w2 + (size_t)l * SQ_P, fb[15 + l], pscr + (size_t)(15 + l) * 65536};
    ft.d[21] = {upd_w2 + (size_t)5 * SQ_P, fb[21], pscr + (size_t)21 * 65536};
    fold_gemm<<<22 * 16, 256, 0, stream>>>(ft);

    // ---- convert pass 2: folded fp32 products -> fp16 planes ----
    CTab ct2;
    nd = 0; tiles = 0;
    for (int l = 1; l < L; ++l) {
        addDesc(ct2, pscr + (size_t)(l - 1) * 65536, wPQR[l],             256, 256, 256);
        addDesc(ct2, pscr + (size_t)(4 + l) * 65536, wPQR[l] + SQ_P,      256, 256, 256);
        addDesc(ct2, pscr + (size_t)(9 + l) * 65536, wPQR[l] + 2 * SQ_P,  256, 256, 256);
    }
    for (int l = 0; l < L; ++l)
        addDesc(ct2, pscr + (size_t)(15 + l) * 65536, wM3_[l], 256, 256, 256);
    addDesc(ct2, pscr + (size_t)21 * 65536, wF, 256, 256, 256);
    ct2.nd = nd;
    convert_weights<<<tiles, 256, 0, stream>>>(ct2);

    // ---- folded bias vectors ----
    BTab bt;
    for (int l = 0; l < L; ++l) {
        const float* ub2p = (l > 0) ? upd_b2 + (size_t)(l - 1) * 256 : nullptr;
        bt.d[l] = {bvec + (size_t)l * 256, msg_b1 + (size_t)l * 256,
                   ub2p, msg_w1 + (size_t)l * 518 * 256,
                   ub2p, msg_w1 + (size_t)l * 518 * 256 + 256 * 256};
        bt.d[6 + l] = {bvec + (size_t)(6 + l) * 256, upd_b1 + (size_t)l * 256,
                       ub2p, upd_w1 + (size_t)l * 512 * 256, nullptr, nullptr};
        bt.d[12 + l] = {bvec + (size_t)(12 + l) * 256, nullptr,
                        msg_b2 + (size_t)l * 256, upd_w1 + (size_t)l * 512 * 256 + 256 * 256,
                        nullptr, nullptr};
    }
    bt.d[18] = {bvec + (size_t)18 * 256, r_b1, upd_b2 + (size_t)5 * 256, r_w1,
                nullptr, nullptr};
    biasvec_kernel<<<19, 256, 0, stream>>>(bt);

    const int mblk = (N + 63) / 64;
    dim3 blk(256);

    // embed: U0 = atom @ emb_w + emb_b
    mfma_gemm<2><<<dim3(mblk, 4), blk, 0, stream>>>(
        atomH, 64, w_emb, 64,
        emb_b, nullptr, nullptr, nullptr, 0,
        bufX0, N, HID, 0);

    __half* U_prev = bufX0;
    __half* U_next = bufX1;
    for (int l = 0; l < L; ++l) {
        const float* w1c = msg_w1 + (size_t)l * 518 * 256 + 512 * 256;

        // PQR = U_prev @ [M1a|M1b|M2]  (Nc=768)
        mfma_gemm<4><<<dim3(mblk, 6), blk, 0, stream>>>(
            U_prev, HID, wPQR[l], HID,
            nullptr, nullptr, nullptr, nullptr, 0,
            PQR, N, 768, 0);
        // Hagg[v] = sum_e relu(P[src]+Q[v]+bagg+ef@W1c)
        aggregate_kernel<<<(N + 3) / 4, blk, 0, stream>>>(
            PQR, bvec + (size_t)l * 256, ef8, offs, csr_src, w1c, HaggH, N);
        // U = relu(Hagg@M3 + R + cb_u + deg.*db)
        mfma_gemm<2><<<dim3(mblk, 4), blk, 0, stream>>>(
            HaggH, HID, wM3_[l], HID,
            bvec + (size_t)(6 + l) * 256, bvec + (size_t)(12 + l) * 256, degf,
            PQR + 512, 768,
            U_next, N, HID, 1);
        __half* t = U_prev; U_prev = U_next; U_next = t;
    }

    // readout: h1 = relu(U5@F + cb_r); h2 = relu(h1@r_w2 + r_b2); mean dot
    mfma_gemm<2><<<dim3(mblk, 4), blk, 0, stream>>>(
        U_prev, HID, wF, HID,
        bvec + (size_t)18 * 256, nullptr, nullptr, nullptr, 0,
        U_next, N, HID, 1);
    mfma_gemm<2><<<dim3(mblk, 2), blk, 0, stream>>>(
        U_next, HID, w_r2, HID,
        r_b2, nullptr, nullptr, nullptr, 0,
        HaggH, N, 128, 1);
    readout_dot_kernel<<<256, blk, 0, stream>>>(HaggH, r_w3, accum, N);
    finalize_kernel<<<1, 1, 0, stream>>>(accum, r_b3, (float*)d_out, 1.0f / (float)N);
}

// Round 7
// 546.680 us; speedup vs baseline: 1.1541x; 1.0349x over previous
//
#include <hip/hip_runtime.h>
#include <hip/hip_bf16.h>
#include <hip/hip_fp16.h>

// ---------------------------------------------------------------------------
// MPNN binding-affinity predictor. R7:
//  - GEMM K-loop double-buffered: 2 LDS buffer sets, next-tile DMA issued
//    before current-tile wait; raw s_barrier + manual s_waitcnt vmcnt(N)
//    (no full vmcnt(0) drain per iteration)
//  - aggregate: 2 edges per half-wave in compute + 2 prefetched (4 gathers
//    in flight per lane)
//  - rest identical to R6 (fp16 MFMA, PQR fusion, weight folding)
// ---------------------------------------------------------------------------

#define HID 256

typedef _Float16 h8 __attribute__((ext_vector_type(8)));
typedef float f32x4 __attribute__((ext_vector_type(4)));

__device__ __forceinline__ void unpack_h8(const int4& r, float* f) {
    const __half2* h = reinterpret_cast<const __half2*>(&r);
#pragma unroll
    for (int k = 0; k < 4; ++k) {
        float2 t = __half22float2(h[k]);
        f[2 * k] = t.x;
        f[2 * k + 1] = t.y;
    }
}

// async global -> LDS 16B DMA; dest wave-uniform, lane i lands at dest+16*i
__device__ __forceinline__ void gld16(const void* g, void* l) {
    __builtin_amdgcn_global_load_lds(
        (const __attribute__((address_space(1))) void*)g,
        (__attribute__((address_space(3))) void*)l, 16, 0, 0);
}

// XOR swizzle of 16B k-segments per row; fragment reads <=2-way (free)
__device__ __forceinline__ int swz(int row) { return (row + (row >> 2)) & 3; }

// ------------------------------ CSR build ----------------------------------

__global__ void hist_kernel(const int* __restrict__ dst, int* __restrict__ deg, int E) {
    int i = blockIdx.x * blockDim.x + threadIdx.x;
    if (i < E) atomicAdd(&deg[dst[i]], 1);
}

__global__ __launch_bounds__(256) void scan_kernel(
    const int* __restrict__ deg, int* __restrict__ offs, float* __restrict__ degf, int n) {
    __shared__ int ws[4];
    const int t = threadIdx.x;
    const int lane = t & 63;
    const int w = t >> 6;
    const int per = (n + 255) / 256;
    const int s = t * per;
    const int e = min(s + per, n);
    int sum = 0;
    for (int i = s; i < e; ++i) sum += deg[i];
    int v = sum;
#pragma unroll
    for (int off = 1; off < 64; off <<= 1) {
        int u = __shfl_up(v, off, 64);
        if (lane >= off) v += u;
    }
    if (lane == 63) ws[w] = v;
    __syncthreads();
    if (t == 0) {
        int c = 0;
#pragma unroll
        for (int i = 0; i < 4; ++i) { int x = ws[i]; ws[i] = c; c += x; }
    }
    __syncthreads();
    int run = ws[w] + v - sum;
    for (int i = s; i < e; ++i) {
        int d = deg[i];
        offs[i] = run;
        degf[i] = (float)d;
        run += d;
    }
    if (e == n) offs[n] = run;
}

__global__ void scatter_kernel(const int* __restrict__ src, const int* __restrict__ dst,
                               const int* __restrict__ offs, int* __restrict__ cursor,
                               int* __restrict__ csr_src, const float* __restrict__ ef,
                               __half* __restrict__ ef8, int E) {
    int i = blockIdx.x * blockDim.x + threadIdx.x;
    if (i < E) {
        int d = dst[i];
        int pos = atomicAdd(&cursor[d], 1);
        int idx = offs[d] + pos;
        csr_src[idx] = src[i];
        const float* s6 = ef + (size_t)i * 6;
        unsigned short h[8];
#pragma unroll
        for (int j = 0; j < 6; ++j) h[j] = __half_as_ushort(__float2half_rn(s6[j]));
        h[6] = 0; h[7] = 0;
        int4 pk;
        pk.x = (int)(h[0] | ((unsigned)h[1] << 16));
        pk.y = (int)(h[2] | ((unsigned)h[3] << 16));
        pk.z = (int)(h[4] | ((unsigned)h[5] << 16));
        pk.w = (int)(h[6] | ((unsigned)h[7] << 16));
        *reinterpret_cast<int4*>(ef8 + (size_t)idx * 8) = pk;
    }
}

// ----------------------- folded bias vectors -------------------------------

struct BDesc { float* out; const float* base; const float* v1; const float* B1;
               const float* v2; const float* B2; };
struct BTab { BDesc d[19]; };

__global__ __launch_bounds__(256) void biasvec_kernel(BTab tab) {
    const BDesc d = tab.d[blockIdx.x];
    const int j = threadIdx.x;
    float acc = d.base ? d.base[j] : 0.f;
    if (d.v1)
        for (int k = 0; k < 256; ++k) acc = fmaf(d.v1[k], d.B1[(size_t)k * 256 + j], acc);
    if (d.v2)
        for (int k = 0; k < 256; ++k) acc = fmaf(d.v2[k], d.B2[(size_t)k * 256 + j], acc);
    d.out[j] = acc;
}

// ------------------------ weight convert -----------------------------------
// src [Kreal, srcN] fp32 row-major -> dst [srcN][Kpad] fp16 (transposed).

struct CDesc {
    const float* src;
    __half* dst;
    int Kreal, Kpad, srcN, tile0;
};
struct CTab {
    CDesc d[32];
    int nd;
};

__global__ __launch_bounds__(256) void convert_weights(CTab tab) {
    const int bid = blockIdx.x;
    int idx = 0;
    for (int i = 1; i < tab.nd; ++i)
        if (tab.d[i].tile0 <= bid) idx = i;
    const CDesc d = tab.d[idx];
    const int q = bid - d.tile0;
    const int ntN = d.srcN >> 6;
    const int kb = (q / ntN) * 32;
    const int nb = (q % ntN) * 64;
    const int n = nb + (threadIdx.x & 63);
    const int k0 = kb + (threadIdx.x >> 6) * 8;
    h8 v;
#pragma unroll
    for (int j = 0; j < 8; ++j) {
        int k = k0 + j;
        v[j] = (_Float16)((k < d.Kreal) ? d.src[(size_t)k * d.srcN + n] : 0.f);
    }
    *reinterpret_cast<h8*>(&d.dst[(size_t)n * d.Kpad + k0]) = v;
}

// ------------------- activation fp32 -> fp16 (pad cols) --------------------

__global__ __launch_bounds__(256) void act_convert(
    const float* __restrict__ src, __half* __restrict__ dst,
    int rows, int scols, int dcols) {
    const int nseg = dcols >> 3;
    int t = blockIdx.x * blockDim.x + threadIdx.x;
    if (t >= rows * nseg) return;
    int r = t / nseg, seg = t - r * nseg;
    h8 v;
#pragma unroll
    for (int j = 0; j < 8; ++j) {
        int c = seg * 8 + j;
        v[j] = (_Float16)((c < scols) ? src[(size_t)r * scols + c] : 0.f);
    }
    *reinterpret_cast<h8*>(&dst[(size_t)r * dcols + seg * 8]) = v;
}

// ------------------- batched fold GEMM (fp16 MFMA) -------------------------
// C[256,256] fp32 = A[256,256] fp32 (cvt fp16 in-kernel) @ B (fp16 [n][k]).

#define ASTR 40

struct FDesc { const float* A; const __half* B; float* C; };
struct FTab { FDesc d[22]; };

__global__ __launch_bounds__(256) void fold_gemm(FTab tab) {
    const FDesc dd = tab.d[blockIdx.x >> 4];
    const int t4 = blockIdx.x & 15;
    const int rowBase = (t4 >> 2) * 64;
    const int colBase = (t4 & 3) * 64;

    __shared__ __align__(16) _Float16 Ah[64 * ASTR];
    __shared__ __align__(16) _Float16 Bh[64 * ASTR];

    const int tid = threadIdx.x;
    const int lane = tid & 63;
    const int wave = tid >> 6;
    const int waveM = (wave >> 1) * 32;
    const int waveN = (wave & 1) * 32;
    const int m0 = lane & 15;
    const int quad = lane >> 4;
    const int sr = tid >> 2;
    const int sseg = tid & 3;

    const f32x4 z = {0.f, 0.f, 0.f, 0.f};
    f32x4 acc[2][2] = {{z, z}, {z, z}};

    for (int kb = 0; kb < 256; kb += 32) {
        {
            const float* Ap = dd.A + (size_t)(rowBase + sr) * 256 + kb + sseg * 8;
            float4 u0 = *reinterpret_cast<const float4*>(Ap);
            float4 u1 = *reinterpret_cast<const float4*>(Ap + 4);
            h8 v;
            v[0] = (_Float16)u0.x; v[1] = (_Float16)u0.y;
            v[2] = (_Float16)u0.z; v[3] = (_Float16)u0.w;
            v[4] = (_Float16)u1.x; v[5] = (_Float16)u1.y;
            v[6] = (_Float16)u1.z; v[7] = (_Float16)u1.w;
            *reinterpret_cast<h8*>(&Ah[sr * ASTR + sseg * 8]) = v;
        }
        {
            size_t off = (size_t)(colBase + sr) * 256 + kb + sseg * 8;
            *reinterpret_cast<int4*>(&Bh[sr * ASTR + sseg * 8]) =
                *reinterpret_cast<const int4*>(&dd.B[off]);
        }
        __syncthreads();

        const h8 a0 = *reinterpret_cast<const h8*>(&Ah[(waveM + m0) * ASTR + quad * 8]);
        const h8 a1 = *reinterpret_cast<const h8*>(&Ah[(waveM + 16 + m0) * ASTR + quad * 8]);
        const h8 b0 = *reinterpret_cast<const h8*>(&Bh[(waveN + m0) * ASTR + quad * 8]);
        const h8 b1 = *reinterpret_cast<const h8*>(&Bh[(waveN + 16 + m0) * ASTR + quad * 8]);

        acc[0][0] = __builtin_amdgcn_mfma_f32_16x16x32_f16(a0, b0, acc[0][0], 0, 0, 0);
        acc[0][1] = __builtin_amdgcn_mfma_f32_16x16x32_f16(a0, b1, acc[0][1], 0, 0, 0);
        acc[1][0] = __builtin_amdgcn_mfma_f32_16x16x32_f16(a1, b0, acc[1][0], 0, 0, 0);
        acc[1][1] = __builtin_amdgcn_mfma_f32_16x16x32_f16(a1, b1, acc[1][1], 0, 0, 0);

        __syncthreads();
    }

#pragma unroll
    for (int tm = 0; tm < 2; ++tm)
#pragma unroll
        for (int reg = 0; reg < 4; ++reg) {
            int row = rowBase + waveM + tm * 16 + quad * 4 + reg;
#pragma unroll
            for (int tn = 0; tn < 2; ++tn) {
                int col = colBase + waveN + tn * 16 + m0;
                dd.C[(size_t)row * 256 + col] = acc[tm][tn][reg];
            }
        }
}

// ------------------------------ MFMA GEMM ----------------------------------
// C = act( A@W + bias + rowscale.*bias2 + addend ), all fp16 in / fp16 out,
// fp32 accumulate. Tile 64 x (TN*32), BK=32, 4 waves 2x2.
// Double-buffered K-loop: 2 LDS buffer sets; next-tile global_load_lds issued
// BEFORE waiting on the current tile; raw s_barrier + manual s_waitcnt
// vmcnt(N) so prefetch loads stay in flight across the barrier. All waitcnt
// paths are block-uniform (no divergent issue counts).

template <int TN>
__global__ __launch_bounds__(256) void mfma_gemm(
    const __half* __restrict__ A, int lda,
    const __half* __restrict__ W, int K,
    const float* __restrict__ bias, const float* __restrict__ bias2,
    const float* __restrict__ rowscale,
    const __half* __restrict__ addend, int astride,
    __half* __restrict__ C, int M, int Nc, int do_relu) {
    constexpr int BUF = 4096 + TN * 2048;  // bytes per buffer set
    __shared__ __align__(16) unsigned char lds[2 * BUF];

    const int tid = threadIdx.x;
    const int lane = tid & 63;
    const int wave = tid >> 6;
    const int m0 = lane & 15;
    const int quad = lane >> 4;
    const int waveM = (wave >> 1) * 32;
    const int waveN = (wave & 1) * (TN * 16);
    const int rowBase = blockIdx.x * 64;
    const int colBase = blockIdx.y * (TN * 32);

    const int sa_r = tid >> 2;
    const int sa_ks = (tid & 3) ^ swz(sa_r);
    const int sa_row = min(rowBase + sa_r, M - 1);
    const int sb_r1 = sa_r + 64;
    const int sb_ks1 = (tid & 3) ^ swz(sb_r1);

    int aoff[2], boff[TN];
#pragma unroll
    for (int tm = 0; tm < 2; ++tm) {
        int r = waveM + tm * 16 + m0;
        aoff[tm] = ((r << 2) + (quad ^ swz(r))) << 4;
    }
#pragma unroll
    for (int tn = 0; tn < TN; ++tn) {
        int r = waveN + tn * 16 + m0;
        boff[tn] = 4096 + (((r << 2) + (quad ^ swz(r))) << 4);
    }

    const f32x4 z = {0.f, 0.f, 0.f, 0.f};
    f32x4 acc[2][TN];
#pragma unroll
    for (int tm = 0; tm < 2; ++tm)
#pragma unroll
        for (int tn = 0; tn < TN; ++tn) acc[tm][tn] = z;

    const __half* ga = A + (size_t)sa_row * lda + sa_ks * 8;
    const __half* gb0 = W + (size_t)(colBase + sa_r) * K + sa_ks * 8;
    const __half* gb1 = W + (size_t)(colBase + sb_r1) * K + sb_ks1 * 8;

    auto issue = [&](int p, int kb) {
        unsigned char* base = lds + p * BUF;
        gld16(ga + kb, base + wave * 1024);
        gld16(gb0 + kb, base + 4096 + wave * 1024);
        if constexpr (TN == 4) gld16(gb1 + kb, base + 8192 + wave * 1024);
    };

    issue(0, 0);
    int p = 0;
    for (int kb = 0; kb < K; kb += 32) {
        const bool has_next = (kb + 32 < K);
        if (has_next) issue(p ^ 1, kb + 32);
        // wait: only the (has_next ? nloads : 0) newest loads may remain
        if (has_next) {
            if constexpr (TN == 4)
                asm volatile("s_waitcnt vmcnt(3)" ::: "memory");
            else
                asm volatile("s_waitcnt vmcnt(2)" ::: "memory");
        } else {
            asm volatile("s_waitcnt vmcnt(0)" ::: "memory");
        }
        asm volatile("s_barrier" ::: "memory");

        const unsigned char* base = lds + p * BUF;
        h8 ah[2], bh[TN];
#pragma unroll
        for (int tm = 0; tm < 2; ++tm)
            ah[tm] = *reinterpret_cast<const h8*>(base + aoff[tm]);
#pragma unroll
        for (int tn = 0; tn < TN; ++tn)
            bh[tn] = *reinterpret_cast<const h8*>(base + boff[tn]);
#pragma unroll
        for (int tm = 0; tm < 2; ++tm)
#pragma unroll
            for (int tn = 0; tn < TN; ++tn)
                acc[tm][tn] = __builtin_amdgcn_mfma_f32_16x16x32_f16(
                    ah[tm], bh[tn], acc[tm][tn], 0, 0, 0);
        // protect buffer p from being overwritten by next iteration's issue
        asm volatile("s_waitcnt lgkmcnt(0)" ::: "memory");
        asm volatile("s_barrier" ::: "memory");
        p ^= 1;
    }

    // epilogue
    float cb[TN], db[TN];
    int col[TN];
#pragma unroll
    for (int tn = 0; tn < TN; ++tn) {
        col[tn] = colBase + waveN + tn * 16 + m0;
        cb[tn] = bias ? bias[col[tn]] : 0.f;
        db[tn] = bias2 ? bias2[col[tn]] : 0.f;
    }
#pragma unroll
    for (int tm = 0; tm < 2; ++tm) {
#pragma unroll
        for (int reg = 0; reg < 4; ++reg) {
            int row = rowBase + waveM + tm * 16 + quad * 4 + reg;
            if (row >= M) continue;
            float rs = rowscale ? rowscale[row] : 0.0f;
#pragma unroll
            for (int tn = 0; tn < TN; ++tn) {
                float v = acc[tm][tn][reg] + cb[tn] + rs * db[tn];
                if (addend)
                    v += __half2float(addend[(size_t)row * astride + col[tn]]);
                if (do_relu) v = fmaxf(v, 0.f);
                C[(size_t)row * Nc + col[tn]] = __float2half_rn(v);
            }
        }
    }
}

// --------------------------- edge aggregation ------------------------------
// Hagg[v] = sum_{e=(s,v)} relu(P[s] + Q[v] + bagg + ef_e @ W1c).
// PQR fp16 [N][768]. One wave/node; each half-wave keeps 2 edges in compute
// and 2 prefetched (4 gathers in flight per lane).

__global__ __launch_bounds__(256) void aggregate_kernel(
    const __half* __restrict__ PQ, const float* __restrict__ bagg,
    const __half* __restrict__ ef8, const int* __restrict__ offs,
    const int* __restrict__ csr_src, const float* __restrict__ W1c,
    __half* __restrict__ Hagg, int n) {
    const int wave = threadIdx.x >> 6;
    const int lane = threadIdx.x & 63;
    const int node = blockIdx.x * 4 + wave;
    if (node >= n) return;
    const int hw = lane >> 5;
    const int sl = lane & 31;
    const int ch = sl * 8;

    float wc[6][8];
#pragma unroll
    for (int k = 0; k < 6; ++k) {
        float4 w0 = *reinterpret_cast<const float4*>(W1c + k * HID + ch);
        float4 w1 = *reinterpret_cast<const float4*>(W1c + k * HID + ch + 4);
        wc[k][0] = w0.x; wc[k][1] = w0.y; wc[k][2] = w0.z; wc[k][3] = w0.w;
        wc[k][4] = w1.x; wc[k][5] = w1.y; wc[k][6] = w1.z; wc[k][7] = w1.w;
    }
    float qb[8];
    {
        int4 r = *reinterpret_cast<const int4*>(PQ + (size_t)node * 768 + 256 + ch);
        unpack_h8(r, qb);
        float4 b0 = *reinterpret_cast<const float4*>(bagg + ch);
        float4 b1 = *reinterpret_cast<const float4*>(bagg + ch + 4);
        qb[0] += b0.x; qb[1] += b0.y; qb[2] += b0.z; qb[3] += b0.w;
        qb[4] += b1.x; qb[5] += b1.y; qb[6] += b1.z; qb[7] += b1.w;
    }
    float acc[8] = {0.f, 0.f, 0.f, 0.f, 0.f, 0.f, 0.f, 0.f};

    auto fma_edge = [&](const int4& praw, const int4& eraw) {
        float p[8], e[8];
        unpack_h8(praw, p);
        unpack_h8(eraw, e);
#pragma unroll
        for (int i = 0; i < 8; ++i) {
            float h = p[i] + qb[i];
            h = fmaf(e[0], wc[0][i], h);
            h = fmaf(e[1], wc[1][i], h);
            h = fmaf(e[2], wc[2][i], h);
            h = fmaf(e[3], wc[3][i], h);
            h = fmaf(e[4], wc[4][i], h);
            h = fmaf(e[5], wc[5][i], h);
            acc[i] += fmaxf(h, 0.f);
        }
    };

    const int beg = offs[node];
    const int end = offs[node + 1];
    int j = beg + hw;
    const int4 z4 = {0, 0, 0, 0};
    int4 pA = z4, eA = z4, pB = z4, eB = z4;
    bool vA = j < end, vB = (j + 2) < end;
    if (vA) {
        int s = csr_src[j];
        eA = *reinterpret_cast<const int4*>(ef8 + (size_t)j * 8);
        pA = *reinterpret_cast<const int4*>(PQ + (size_t)s * 768 + ch);
    }
    if (vB) {
        int s = csr_src[j + 2];
        eB = *reinterpret_cast<const int4*>(ef8 + (size_t)(j + 2) * 8);
        pB = *reinterpret_cast<const int4*>(PQ + (size_t)s * 768 + ch);
    }
    while (vA) {
        int4 pC = z4, eC = z4, pD = z4, eD = z4;
        bool vC = (j + 4) < end, vD = (j + 6) < end;
        if (vC) {
            int s = csr_src[j + 4];
            eC = *reinterpret_cast<const int4*>(ef8 + (size_t)(j + 4) * 8);
            pC = *reinterpret_cast<const int4*>(PQ + (size_t)s * 768 + ch);
        }
        if (vD) {
            int s = csr_src[j + 6];
            eD = *reinterpret_cast<const int4*>(ef8 + (size_t)(j + 6) * 8);
            pD = *reinterpret_cast<const int4*>(PQ + (size_t)s * 768 + ch);
        }
        fma_edge(pA, eA);
        if (vB) fma_edge(pB, eB);
        j += 4;
        pA = pC; eA = eC; vA = vC;
        pB = pD; eB = eD; vB = vD;
    }
    unsigned short hs[8];
#pragma unroll
    for (int i = 0; i < 8; ++i) {
        float tot = acc[i] + __shfl_down(acc[i], 32, 64);
        hs[i] = __half_as_ushort(__float2half_rn(tot));
    }
    if (hw == 0) {
        int4 pk;
        pk.x = (int)(hs[0] | ((unsigned)hs[1] << 16));
        pk.y = (int)(hs[2] | ((unsigned)hs[3] << 16));
        pk.z = (int)(hs[4] | ((unsigned)hs[5] << 16));
        pk.w = (int)(hs[6] | ((unsigned)hs[7] << 16));
        *reinterpret_cast<int4*>(Hagg + (size_t)node * HID + ch) = pk;
    }
}

// ------------------------------- readout -----------------------------------

__global__ __launch_bounds__(256) void readout_dot_kernel(
    const __half* __restrict__ h2, const float* __restrict__ w3,
    float* __restrict__ accum, int n) {
    const int wave = threadIdx.x >> 6;
    const int lane = threadIdx.x & 63;
    const int nwaves = gridDim.x * 4;
    const int wid = blockIdx.x * 4 + wave;
    const float2 w = *reinterpret_cast<const float2*>(w3 + lane * 2);
    float local = 0.f;
    for (int node = wid; node < n; node += nwaves) {
        __half2 v = *reinterpret_cast<const __half2*>(h2 + (size_t)node * 128 + lane * 2);
        float2 vf = __half22float2(v);
        local = fmaf(vf.x, w.x, local);
        local = fmaf(vf.y, w.y, local);
    }
    for (int off = 32; off > 0; off >>= 1) local += __shfl_down(local, off, 64);
    if (lane == 0) atomicAdd(accum, local);
}

__global__ void finalize_kernel(const float* __restrict__ accum, const float* __restrict__ b3,
                                float* __restrict__ out, float inv_n) {
    out[0] = accum[0] * inv_n + b3[0];
}

// ------------------------------- driver ------------------------------------

extern "C" void kernel_launch(void* const* d_in, const int* in_sizes, int n_in,
                              void* d_out, int out_size, void* d_ws, size_t ws_size,
                              hipStream_t stream) {
    const float* atom   = (const float*)d_in[0];
    const int*   eidx   = (const int*)d_in[1];
    const float* ef     = (const float*)d_in[2];
    const float* emb_w  = (const float*)d_in[3];
    const float* emb_b  = (const float*)d_in[4];
    const float* msg_w1 = (const float*)d_in[5];
    const float* msg_b1 = (const float*)d_in[6];
    const float* msg_w2 = (const float*)d_in[7];
    const float* msg_b2 = (const float*)d_in[8];
    const float* upd_w1 = (const float*)d_in[9];
    const float* upd_b1 = (const float*)d_in[10];
    const float* upd_w2 = (const float*)d_in[11];
    const float* upd_b2 = (const float*)d_in[12];
    const float* r_w1   = (const float*)d_in[13];
    const float* r_b1   = (const float*)d_in[14];
    const float* r_w2   = (const float*)d_in[15];
    const float* r_b2   = (const float*)d_in[16];
    const float* r_w3   = (const float*)d_in[17];
    const float* r_b3   = (const float*)d_in[18];

    const int N = in_sizes[0] / 62;
    const int E = in_sizes[1] / 2;
    const int L = in_sizes[5] / (518 * 256);
    const int* src = eidx;
    const int* dst = eidx + E;

    char* wp = (char*)d_ws;
    auto alloc = [&](size_t bytes) -> void* {
        void* p = (void*)wp;
        wp += (bytes + 255) & ~(size_t)255;
        return p;
    };
    int*   deg     = (int*)alloc((size_t)N * 4);
    int*   cursor  = (int*)alloc((size_t)N * 4);
    float* accum   = (float*)alloc(256);
    size_t zero_bytes = (size_t)((char*)accum - (char*)d_ws) + 256;
    float* degf    = (float*)alloc((size_t)N * 4);
    int*   offs    = (int*)alloc((size_t)(N + 1) * 4);
    int*   csr_src = (int*)alloc((size_t)E * 4);
    __half* ef8    = (__half*)alloc((size_t)E * 8 * 2);

    const int SQ_P = 256 * 256;
    __half* w_emb = (__half*)alloc((size_t)256 * 64 * 2);
    __half* w_r2  = (__half*)alloc((size_t)128 * 256 * 2);
    __half* wF    = (__half*)alloc((size_t)SQ_P * 2);
    __half *wPQR[6], *wM3_[6];
    for (int l = 0; l < L; ++l) {
        wPQR[l] = (__half*)alloc((size_t)768 * 256 * 2);
        wM3_[l] = (__half*)alloc((size_t)SQ_P * 2);
    }
    __half* fb[22];
    for (int i = 0; i < 22; ++i) fb[i] = (__half*)alloc((size_t)SQ_P * 2);
    float* pscr = (float*)alloc((size_t)22 * 65536 * 4);
    float* bvec = (float*)alloc((size_t)19 * 256 * 4);

    __half* atomH = (__half*)alloc((size_t)N * 64 * 2);
    __half* bufX0 = (__half*)alloc((size_t)N * HID * 2);
    __half* bufX1 = (__half*)alloc((size_t)N * HID * 2);
    __half* PQR   = (__half*)alloc((size_t)N * 768 * 2);
    __half* HaggH = (__half*)alloc((size_t)N * HID * 2);

    hipMemsetAsync(d_ws, 0, zero_bytes, stream);

    // ---- CSR build ----
    hist_kernel<<<(E + 255) / 256, 256, 0, stream>>>(dst, deg, E);
    scan_kernel<<<1, 256, 0, stream>>>(deg, offs, degf, N);
    scatter_kernel<<<(E + 255) / 256, 256, 0, stream>>>(src, dst, offs, cursor,
                                                        csr_src, ef, ef8, E);
    act_convert<<<(N * 8 + 255) / 256, 256, 0, stream>>>(atom, atomH, N, 62, 64);

    // ---- convert pass 1 ----
    CTab ct1;
    int nd = 0, tiles = 0;
    auto addDesc = [&](CTab& ct, const float* s, __half* dh, int Kreal, int Kpad,
                       int srcN) {
        ct.d[nd] = {s, dh, Kreal, Kpad, srcN, tiles};
        tiles += (Kpad / 32) * (srcN / 64);
        ++nd;
    };
    addDesc(ct1, emb_w, w_emb, 62, 64, 256);
    addDesc(ct1, msg_w1, wPQR[0], 256, 256, 256);
    addDesc(ct1, msg_w1 + 256 * 256, wPQR[0] + SQ_P, 256, 256, 256);
    addDesc(ct1, upd_w1, wPQR[0] + 2 * SQ_P, 256, 256, 256);
    addDesc(ct1, r_w2, w_r2, 256, 256, 128);
    for (int l = 1; l < L; ++l) {
        addDesc(ct1, msg_w1 + (size_t)l * 518 * 256,             fb[l - 1], 256, 256, 256);
        addDesc(ct1, msg_w1 + (size_t)l * 518 * 256 + 256 * 256, fb[4 + l], 256, 256, 256);
        addDesc(ct1, upd_w1 + (size_t)l * 512 * 256,             fb[9 + l], 256, 256, 256);
    }
    for (int l = 0; l < L; ++l)
        addDesc(ct1, upd_w1 + (size_t)l * 512 * 256 + 256 * 256, fb[15 + l], 256, 256, 256);
    addDesc(ct1, r_w1, fb[21], 256, 256, 256);
    ct1.nd = nd;
    convert_weights<<<tiles, 256, 0, stream>>>(ct1);

    // ---- fold GEMMs (fp16 MFMA) ----
    FTab ft;
    for (int l = 1; l < L; ++l) {
        const float* U2p = upd_w2 + (size_t)(l - 1) * SQ_P;
        ft.d[l - 1] = {U2p, fb[l - 1], pscr + (size_t)(l - 1) * 65536};
        ft.d[4 + l] = {U2p, fb[4 + l], pscr + (size_t)(4 + l) * 65536};
        ft.d[9 + l] = {U2p, fb[9 + l], pscr + (size_t)(9 + l) * 65536};
    }
    for (int l = 0; l < L; ++l)
        ft.d[15 + l] = {msg_w2 + (size_t)l * SQ_P, fb[15 + l], pscr + (size_t)(15 + l) * 65536};
    ft.d[21] = {upd_w2 + (size_t)5 * SQ_P, fb[21], pscr + (size_t)21 * 65536};
    fold_gemm<<<22 * 16, 256, 0, stream>>>(ft);

    // ---- convert pass 2 ----
    CTab ct2;
    nd = 0; tiles = 0;
    for (int l = 1; l < L; ++l) {
        addDesc(ct2, pscr + (size_t)(l - 1) * 65536, wPQR[l],             256, 256, 256);
        addDesc(ct2, pscr + (size_t)(4 + l) * 65536, wPQR[l] + SQ_P,      256, 256, 256);
        addDesc(ct2, pscr + (size_t)(9 + l) * 65536, wPQR[l] + 2 * SQ_P,  256, 256, 256);
    }
    for (int l = 0; l < L; ++l)
        addDesc(ct2, pscr + (size_t)(15 + l) * 65536, wM3_[l], 256, 256, 256);
    addDesc(ct2, pscr + (size_t)21 * 65536, wF, 256, 256, 256);
    ct2.nd = nd;
    convert_weights<<<tiles, 256, 0, stream>>>(ct2);

    // ---- folded bias vectors ----
    BTab bt;
    for (int l = 0; l < L; ++l) {
        const float* ub2p = (l > 0) ? upd_b2 + (size_t)(l - 1) * 256 : nullptr;
        bt.d[l] = {bvec + (size_t)l * 256, msg_b1 + (size_t)l * 256,
                   ub2p, msg_w1 + (size_t)l * 518 * 256,
                   ub2p, msg_w1 + (size_t)l * 518 * 256 + 256 * 256};
        bt.d[6 + l] = {bvec + (size_t)(6 + l) * 256, upd_b1 + (size_t)l * 256,
                       ub2p, upd_w1 + (size_t)l * 512 * 256, nullptr, nullptr};
        bt.d[12 + l] = {bvec + (size_t)(12 + l) * 256, nullptr,
                        msg_b2 + (size_t)l * 256, upd_w1 + (size_t)l * 512 * 256 + 256 * 256,
                        nullptr, nullptr};
    }
    bt.d[18] = {bvec + (size_t)18 * 256, r_b1, upd_b2 + (size_t)5 * 256, r_w1,
                nullptr, nullptr};
    biasvec_kernel<<<19, 256, 0, stream>>>(bt);

    const int mblk = (N + 63) / 64;
    dim3 blk(256);

    // embed: U0 = atom @ emb_w + emb_b
    mfma_gemm<2><<<dim3(mblk, 4), blk, 0, stream>>>(
        atomH, 64, w_emb, 64,
        emb_b, nullptr, nullptr, nullptr, 0,
        bufX0, N, HID, 0);

    __half* U_prev = bufX0;
    __half* U_next = bufX1;
    for (int l = 0; l < L; ++l) {
        const float* w1c = msg_w1 + (size_t)l * 518 * 256 + 512 * 256;

        mfma_gemm<4><<<dim3(mblk, 6), blk, 0, stream>>>(
            U_prev, HID, wPQR[l], HID,
            nullptr, nullptr, nullptr, nullptr, 0,
            PQR, N, 768, 0);
        aggregate_kernel<<<(N + 3) / 4, blk, 0, stream>>>(
            PQR, bvec + (size_t)l * 256, ef8, offs, csr_src, w1c, HaggH, N);
        mfma_gemm<2><<<dim3(mblk, 4), blk, 0, stream>>>(
            HaggH, HID, wM3_[l], HID,
            bvec + (size_t)(6 + l) * 256, bvec + (size_t)(12 + l) * 256, degf,
            PQR + 512, 768,
            U_next, N, HID, 1);
        __half* t = U_prev; U_prev = U_next; U_next = t;
    }

    // readout
    mfma_gemm<2><<<dim3(mblk, 4), blk, 0, stream>>>(
        U_prev, HID, wF, HID,
        bvec + (size_t)18 * 256, nullptr, nullptr, nullptr, 0,
        U_next, N, HID, 1);
    mfma_gemm<2><<<dim3(mblk, 2), blk, 0, stream>>>(
        U_next, HID, w_r2, HID,
        r_b2, nullptr, nullptr, nullptr, 0,
        HaggH, N, 128, 1);
    readout_dot_kernel<<<256, blk, 0, stream>>>(HaggH, r_w3, accum, N);
    finalize_kernel<<<1, 1, 0, stream>>>(accum, r_b3, (float*)d_out, 1.0f / (float)N);
}